// Round 15
// baseline (2482.166 us; speedup 1.0000x reference)
//
#include <hip/hip_runtime.h>

// SDMamba forward. All GEMMs on MFMA f16 (fp32 accumulate); conv/scan/LN fp32 math.
// Segmented scan (p1 local+sum(dt), combine, p2 rescan), 1 lane = 1 chain, 16 states
// in-lane; A_log=log(1..16) fast path (one exp + pow-tree). Conv: rolling window.
// GEMM: 2-phase double-buffered K-loop UNROLLED x2 with LITERAL buffer indices
// (compiler can prove As[0]/As[1] disjoint -> ds_reads overlap in-flight loads);
// fragment-order LDS (512 halves/fragment) -> conflict-free ds_read_b128;
// XCD-chunk swizzle; epilogue RMW prefetch; TN=64 variant for x_proj.

typedef _Float16 f16;
typedef _Float16 f16x8 __attribute__((ext_vector_type(8)));
typedef _Float16 f16x4 __attribute__((ext_vector_type(4)));
typedef float    f32x4 __attribute__((ext_vector_type(4)));

template<bool B> struct BoolC { static constexpr bool value = B; };
template<int V>  struct IntC  { static constexpr int  value = V; };

constexpr int Bb  = 32;
constexpr int Lh  = 96;
constexpr int FUTc= 96;
constexpr int Nn  = 862;
constexpr int Dm  = 512;
constexpr int Ds  = 16;
constexpr int Di  = 1024;
constexpr int DRr = 32;
constexpr int TT  = Bb * Nn;     // 27584
constexpr int NCH = Bb * Di;     // 32768 scan chains
constexpr float EPSf = 1e-5f;

__device__ __forceinline__ float sigm(float x){ return 1.f / (1.f + __expf(-x)); }

__device__ __forceinline__ void gll16(f16* lds, const f16* g){
  __builtin_amdgcn_global_load_lds(
      (const __attribute__((address_space(1))) void*)g,
      (__attribute__((address_space(3)))       void*)lds, 16, 0, 0);
}

// ---------------- RevIN stats ----------------
__global__ __launch_bounds__(256) void stats_kernel(const float* __restrict__ x,
    float* __restrict__ meanb, float* __restrict__ stdb)
{
  int i = blockIdx.x * 256 + threadIdx.x;
  if (i >= TT) return;
  int b = i / Nn, n = i - b * Nn;
  const float* p = x + (size_t)b * Lh * Nn + n;
  float s = 0.f, sq = 0.f;
  #pragma unroll 4
  for (int l = 0; l < Lh; l++){ float v = p[(size_t)l * Nn]; s += v; sq += v * v; }
  float m = s * (1.f / Lh);
  float var = sq * (1.f / Lh) - m * m;
  meanb[i] = m;
  stdb[i]  = sqrtf(var + EPSf);
}

// ---------------- normalize + layout to [tok][L] fp16 ----------------
__global__ __launch_bounds__(256) void prep_kernel(const float* __restrict__ x,
    const float* __restrict__ meanb, const float* __restrict__ stdb,
    const float* __restrict__ rw, const float* __restrict__ rb,
    f16* __restrict__ xn16)
{
  int idx = blockIdx.x * 256 + threadIdx.x;
  if (idx >= Bb * Lh * Nn) return;
  int n  = idx % Nn;
  int bl = idx / Nn;
  int l  = bl % Lh;
  int b  = bl / Lh;
  int tok = b * Nn + n;
  float v = x[idx];
  xn16[(size_t)tok * Lh + l] = (f16)((v - meanb[tok]) / stdb[tok] * rw[n] + rb[n]);
}

// ---------------- f32 -> f16 convert ----------------
__global__ __launch_bounds__(256) void cvt_kernel(const float* __restrict__ in,
    f16* __restrict__ out, int n4)
{
  int i = blockIdx.x * 256 + threadIdx.x;
  if (i >= n4) return;
  float4 v = ((const float4*)in)[i];
  f16x4 h; h[0] = (f16)v.x; h[1] = (f16)v.y; h[2] = (f16)v.z; h[3] = (f16)v.w;
  *(f16x4*)(out + (size_t)i * 4) = h;
}

// ---------------- MFMA GEMM: C[m,o] = act(sum_k A[m,k]*W[o,k] + bias[o]) ----------------
// ACT: 0 none, 1 relu, 2 softplus (fast), 3 silu-gate-RMW on C16 (C16 *= silu(v)).
// ACC: C += (W32 path). W32/W16: write f32 C / f16 C16.
// OMIN: f32 write only for o>=OMIN at col (o-OMIN). OMAX16: f16 write only for o<OMAX16.
// TN: tile width (128 or 64).
template<int ACT, int ACC, int W32, int W16, int OMIN = 0, int OMAX16 = (1 << 30), int TN = 128>
__global__ __launch_bounds__(256) void gemm16_kernel(
    const f16* __restrict__ A, int lda,
    const f16* __restrict__ W, int K,
    const float* __restrict__ bias,
    float* __restrict__ C, int ldc,
    f16* __restrict__ C16, int ldc16,
    int O, int M)
{
  constexpr int JN = (TN == 64) ? 2 : 4;
  __shared__ f16 As[2][128 * 32];
  __shared__ f16 Bs[2][TN * 32];
  const int tid  = threadIdx.x;
  const int lane = tid & 63;
  const int w    = tid >> 6;
  const int wm   = w >> 1, wn = w & 1;
  // XCD-chunk swizzle (bijective, any nwg)
  int bid = blockIdx.y * gridDim.x + blockIdx.x;
  int nwg = gridDim.x * gridDim.y;
  int q = nwg >> 3, r = nwg & 7;
  int xcd = bid & 7, idx = bid >> 3;
  int swz = (xcd < r ? xcd * (q + 1) : r * (q + 1) + (xcd - r) * q) + idx;
  const int m0   = (swz / gridDim.x) * 128, o0 = (swz % gridDim.x) * TN;
  const int wmM  = wm * 64;
  const int wnN  = (TN == 64) ? wn * 32 : wn * 64;
  const int lm   = lane & 15, kg = lane >> 4;
  const int lm16 = lane & 15, kch = lane >> 4;   // staging: row-in-frag, k-chunk

  f32x4 acc[4][JN];
  #pragma unroll
  for (int i = 0; i < 4; i++)
    #pragma unroll
    for (int j = 0; j < JN; j++){ f32x4 z = {0.f,0.f,0.f,0.f}; acc[i][j] = z; }

  auto stage = [&](int buf, int k0){
    int fr0 = 2 * w;                         // this wave's two A fragments
    int r0 = min(m0 + fr0 * 16 + lm16,      M - 1);
    int r1 = min(m0 + fr0 * 16 + 16 + lm16, M - 1);
    gll16(&As[buf][(size_t)fr0 * 512],       A + (size_t)r0 * lda + k0 + kch * 8);
    gll16(&As[buf][(size_t)fr0 * 512 + 512], A + (size_t)r1 * lda + k0 + kch * 8);
    if constexpr (TN == 128){
      int q0 = min(o0 + fr0 * 16 + lm16,      O - 1);
      int q1 = min(o0 + fr0 * 16 + 16 + lm16, O - 1);
      gll16(&Bs[buf][(size_t)fr0 * 512],       W + (size_t)q0 * K + k0 + kch * 8);
      gll16(&Bs[buf][(size_t)fr0 * 512 + 512], W + (size_t)q1 * K + k0 + kch * 8);
    } else {
      int q0 = min(o0 + w * 16 + lm16, O - 1);
      gll16(&Bs[buf][(size_t)w * 512], W + (size_t)q0 * K + k0 + kch * 8);
    }
  };

  auto comp = [&](auto BUFC){
    constexpr int bb = decltype(BUFC)::value;   // literal buffer index
    f16x8 af[4], bf[JN];
    #pragma unroll
    for (int f = 0; f < 4; f++)
      af[f] = *(const f16x8*)&As[bb][(size_t)(wm * 4 + f) * 512 + lane * 8];
    #pragma unroll
    for (int f = 0; f < JN; f++)
      bf[f] = *(const f16x8*)&Bs[bb][(size_t)((TN == 64 ? wn * 2 : wn * 4) + f) * 512 + lane * 8];
    #pragma unroll
    for (int i = 0; i < 4; i++)
      #pragma unroll
      for (int j = 0; j < JN; j++)
        acc[i][j] = __builtin_amdgcn_mfma_f32_16x16x32_f16(af[i], bf[j], acc[i][j], 0, 0, 0);
  };

  const int NIT = K >> 5;
  stage(0, 0);
  __syncthreads();                         // buf0 ready
  int it = 0;
  for (; it + 2 <= NIT; it += 2){
    stage(1, (it + 1) << 5);               // issue next tile (buf1) FIRST
    comp(IntC<0>{});                       // compute buf0 (provably disjoint)
    __syncthreads();                       // drain: buf1 ready
    if (it + 2 < NIT) stage(0, (it + 2) << 5);
    comp(IntC<1>{});
    __syncthreads();
  }
  if (it < NIT) comp(IntC<0>{});           // odd tail (buf0 staged by loop/prologue)

  // ---- epilogue with i-sliced RMW prefetch (ACT3: f16; ACC: f32) ----
  f16   pf16[2][4][JN];
  float pf32[2][4][JN];
  auto ldslice = [&](int i, int bank){
    if constexpr (ACT == 3){
      #pragma unroll
      for (int r2 = 0; r2 < 4; r2++){
        int m = min(m0 + wmM + i * 16 + kg * 4 + r2, M - 1);
        #pragma unroll
        for (int j = 0; j < JN; j++){
          int o = min(o0 + wnN + j * 16 + lm, O - 1);
          pf16[bank][r2][j] = C16[(size_t)m * ldc16 + o];
        }
      }
    }
    if constexpr (ACC == 1){
      #pragma unroll
      for (int r2 = 0; r2 < 4; r2++){
        int m = min(m0 + wmM + i * 16 + kg * 4 + r2, M - 1);
        #pragma unroll
        for (int j = 0; j < JN; j++){
          int o = min(o0 + wnN + j * 16 + lm, O - 1);
          if (o >= OMIN) pf32[bank][r2][j] = C[(size_t)m * ldc + (o - OMIN)];
        }
      }
    }
  };
  ldslice(0, 0);
  #pragma unroll
  for (int i = 0; i < 4; i++){
    if (i < 3) ldslice(i + 1, (i + 1) & 1);
    #pragma unroll
    for (int r2 = 0; r2 < 4; r2++){
      int m = m0 + wmM + i * 16 + kg * 4 + r2;
      if (m >= M) continue;
      #pragma unroll
      for (int j = 0; j < JN; j++){
        int o = o0 + wnN + j * 16 + lm;
        if (o >= O) continue;
        float v = acc[i][j][r2];
        if (bias) v += bias[o];
        if (ACT == 1) v = fmaxf(v, 0.f);
        if (ACT == 2) v = fmaxf(v, 0.f) + __logf(1.f + __expf(-fabsf(v)));
        if (ACT == 3){
          float gate = v * sigm(v);
          C16[(size_t)m * ldc16 + o] = (f16)((float)pf16[i & 1][r2][j] * gate);
        } else {
          if (W32 && o >= OMIN){
            if (ACC) v += pf32[i & 1][r2][j];
            C[(size_t)m * ldc + (o - OMIN)] = v;
          }
          if (W16 && o < OMAX16) C16[(size_t)m * ldc16 + o] = (f16)v;
        }
      }
    }
  }
}

// ---------------- depthwise causal conv (len 4) + SiLU ----------------
// 8 tokens x 8 channels per thread, rolling 4-row register window.
template<int DIR>
__global__ __launch_bounds__(256) void conv2_kernel(
    const f16* __restrict__ x16, const float* __restrict__ w,
    const float* __restrict__ cb, f16* __restrict__ xi16)
{
  constexpr int TG = 8;
  constexpr int NG = (Nn + TG - 1) / TG;       // 108 token-groups
  int idx = blockIdx.x * 256 + threadIdx.x;
  if (idx >= Bb * NG * 128) return;
  int d8 = (idx & 127) << 3;
  int gg = idx >> 7;
  int g  = gg % NG, b = gg / NG;
  int n0 = g * TG;
  const f16* base  = x16  + (size_t)b * Nn * 1024 + d8;
  f16*       obase = xi16 + (size_t)b * Nn * 1024 + d8;

  float bias[8];
  {
    float4 c0 = *(const float4*)(cb + d8), c1 = *(const float4*)(cb + d8 + 4);
    bias[0]=c0.x; bias[1]=c0.y; bias[2]=c0.z; bias[3]=c0.w;
    bias[4]=c1.x; bias[5]=c1.y; bias[6]=c1.z; bias[7]=c1.w;
  }
  float wr[4][8];
  #pragma unroll
  for (int i = 0; i < 8; i++){
    float4 wv = *(const float4*)(w + (size_t)(d8 + i) * 4);
    wr[0][i]=wv.x; wr[1][i]=wv.y; wr[2][i]=wv.z; wr[3][i]=wv.w;
  }

  f16x8 zv;
  #pragma unroll
  for (int i = 0; i < 8; i++) zv[i] = (f16)0.f;

  f16x8 win[4];
  #pragma unroll
  for (int j = 0; j < 3; j++){
    int r = DIR ? (n0 + j) : (n0 - 3 + j);
    bool ok = DIR ? (r < Nn) : (r >= 0);
    win[j] = ok ? *(const f16x8*)(base + (size_t)r * 1024) : zv;
  }
  #pragma unroll
  for (int s = 0; s < TG; s++){
    int n = n0 + s;
    if (n < Nn){
      int r = DIR ? (n + 3) : n;
      bool ok = DIR ? (r < Nn) : true;
      win[3] = ok ? *(const f16x8*)(base + (size_t)r * 1024) : zv;
      float acc[8];
      #pragma unroll
      for (int i = 0; i < 8; i++) acc[i] = bias[i];
      #pragma unroll
      for (int k = 0; k < 4; k++){
        const f16x8& rv = DIR ? win[3 - k] : win[k];
        #pragma unroll
        for (int i = 0; i < 8; i++) acc[i] = fmaf(wr[k][i], (float)rv[i], acc[i]);
      }
      f16x8 o;
      #pragma unroll
      for (int i = 0; i < 8; i++){ float a = acc[i]; o[i] = (f16)(a * sigm(a)); }
      *(f16x8*)(obase + (size_t)n * 1024) = o;
      win[0] = win[1]; win[1] = win[2]; win[2] = win[3];
    }
  }
}

// dA[j] = p^(j+1) for j=0..15 from one exp (tree, depth 4)
__device__ __forceinline__ void pow16(float pp, float* dA){
  float q2 = pp * pp, q3 = q2 * pp, q4 = q2 * q2, q8 = q4 * q4;
  dA[0] = pp;      dA[1] = q2;      dA[2] = q3;      dA[3] = q4;
  dA[4] = q4 * pp; dA[5] = q4 * q2; dA[6] = q4 * q3; dA[7] = q8;
  dA[8] = q8 * pp; dA[9] = q8 * q2; dA[10]= q8 * q3; dA[11]= q8 * q4;
  dA[12]= q8 * dA[4]; dA[13]= q8 * dA[5]; dA[14]= q8 * dA[6]; dA[15]= q8 * q8;
}

template<bool FAST>
__device__ __forceinline__ void mk_dA(float dt, float a0, const float* Aj, float* dA){
  if constexpr (FAST){
    pow16(__expf(dt * a0), dA);
  } else {
    _Pragma("unroll")
    for (int j = 0; j < 16; j++) dA[j] = __expf(dt * Aj[j]);
  }
}

// ---------------- scan pass 1: local h + sum(dt) per segment ----------------
template<int DIR>
__global__ __launch_bounds__(256, 2) void scan_p1_kernel(
    const float* __restrict__ bc, const f16* __restrict__ dt_,
    const f16* __restrict__ xi, const float* __restrict__ A_log,
    float* __restrict__ hseg, float* __restrict__ sdt, int L)
{
  const int seg = blockIdx.y;
  int chain = blockIdx.x * 256 + threadIdx.x;
  int d = chain & 1023;
  int b = __builtin_amdgcn_readfirstlane(chain >> 10);   // wave-uniform (256-aligned blocks)
  float Aj[16];
  #pragma unroll
  for (int q = 0; q < 4; q++){
    float4 al = *(const float4*)(A_log + (size_t)d * 16 + q * 4);
    Aj[q*4+0] = -__expf(al.x); Aj[q*4+1] = -__expf(al.y);
    Aj[q*4+2] = -__expf(al.z); Aj[q*4+3] = -__expf(al.w);
  }
  float a0 = Aj[0];
  int lf = 1;
  #pragma unroll
  for (int j = 1; j < 16; j++)
    lf &= (fabsf(Aj[j] - (j + 1) * a0) <= 2e-3f * (j + 1) * fabsf(a0));
  bool wfast = __all(lf);

  constexpr ptrdiff_t sBC = DIR ? -32 : 32;
  constexpr ptrdiff_t sX  = DIR ? -1024 : 1024;
  int p0 = seg * L;
  size_t tok0 = (size_t)b * Nn + (DIR ? (Nn - 1 - p0) : p0);
  const float* lBC = bc  + tok0 * 32;          // wave-uniform -> scalar loads
  const f16*   lDt = dt_ + tok0 * 1024 + d;
  const f16*   lXi = xi  + tok0 * 1024 + d;

  float h[16];
  #pragma unroll
  for (int j = 0; j < 16; j++) h[j] = 0.f;
  float sacc = 0.f;

  float dtA, xvA, dtB, xvB;
  float4 BA[4], BB[4];

  #define LOADP1(dt_r, xv_r, Bq)                                   \
    { dt_r = (float)*lDt; xv_r = (float)*lXi;                      \
      _Pragma("unroll")                                            \
      for (int q = 0; q < 4; q++) Bq[q] = *(const float4*)(lBC + 4*q); \
      lDt += sX; lXi += sX; lBC += sBC; }

  auto run = [&](auto FAST){
    auto stepv = [&](float dt, float xv, const float4* Bq){
      sacc += dt;
      float dtx = dt * xv;
      float B[16] = {Bq[0].x,Bq[0].y,Bq[0].z,Bq[0].w, Bq[1].x,Bq[1].y,Bq[1].z,Bq[1].w,
                     Bq[2].x,Bq[2].y,Bq[2].z,Bq[2].w, Bq[3].x,Bq[3].y,Bq[3].z,Bq[3].w};
      float dA[16];
      mk_dA<decltype(FAST)::value>(dt, a0, Aj, dA);
      #pragma unroll
      for (int j = 0; j < 16; j++)
        h[j] = fmaf(dA[j], h[j], dtx * B[j]);
    };
    LOADP1(dtA, xvA, BA);
    int t = 0;
    for (; t + 3 <= L; t += 2){
      LOADP1(dtB, xvB, BB);
      asm volatile("" ::: "memory");
      stepv(dtA, xvA, BA);
      LOADP1(dtA, xvA, BA);
      asm volatile("" ::: "memory");
      stepv(dtB, xvB, BB);
    }
    stepv(dtA, xvA, BA); t++;
    if (t < L){ LOADP1(dtB, xvB, BB); stepv(dtB, xvB, BB); }
  };
  if (wfast) run(BoolC<true>{}); else run(BoolC<false>{});
  #undef LOADP1

  float* hp = hseg + ((size_t)seg * NCH + chain) * 16;
  #pragma unroll
  for (int q = 0; q < 4; q++)
    *(float4*)(hp + 4*q) = make_float4(h[q*4], h[q*4+1], h[q*4+2], h[q*4+3]);
  sdt[(size_t)seg * NCH + chain] = sacc;
}

// ---------------- scan combine: hseg[s] := h_in(seg s+1), in place ----------------
__global__ __launch_bounds__(256) void scan_cb_kernel(
    const float* __restrict__ A_log, float* __restrict__ hseg,
    const float* __restrict__ sdt, int Sm1)
{
  int chain = blockIdx.x * 256 + threadIdx.x;
  int d = chain & 1023;
  float Aj[16];
  #pragma unroll
  for (int q = 0; q < 4; q++){
    float4 al = *(const float4*)(A_log + (size_t)d * 16 + q * 4);
    Aj[q*4+0] = -__expf(al.x); Aj[q*4+1] = -__expf(al.y);
    Aj[q*4+2] = -__expf(al.z); Aj[q*4+3] = -__expf(al.w);
  }
  float tacc[16];
  #pragma unroll
  for (int j = 0; j < 16; j++) tacc[j] = 0.f;
  for (int s = 0; s < Sm1; s++){
    float sd = sdt[(size_t)s * NCH + chain];
    float* hp = hseg + ((size_t)s * NCH + chain) * 16;
    #pragma unroll
    for (int q = 0; q < 4; q++){
      float4 hl = *(const float4*)(hp + 4*q);
      tacc[q*4+0] = fmaf(__expf(Aj[q*4+0] * sd), tacc[q*4+0], hl.x);
      tacc[q*4+1] = fmaf(__expf(Aj[q*4+1] * sd), tacc[q*4+1], hl.y);
      tacc[q*4+2] = fmaf(__expf(Aj[q*4+2] * sd), tacc[q*4+2], hl.z);
      tacc[q*4+3] = fmaf(__expf(Aj[q*4+3] * sd), tacc[q*4+3], hl.w);
      *(float4*)(hp + 4*q) = make_float4(tacc[q*4], tacc[q*4+1], tacc[q*4+2], tacc[q*4+3]);
    }
  }
}

// ---------------- scan pass 2: full rescan per segment, y over dt in place ----------------
template<int DIR>
__global__ __launch_bounds__(256, 2) void scan_p2_kernel(
    const float* __restrict__ bc, f16* dty, const f16* __restrict__ xi,
    const float* __restrict__ A_log, const float* __restrict__ Dp,
    const float* __restrict__ hseg, int L)
{
  const int seg = blockIdx.y;
  int chain = blockIdx.x * 256 + threadIdx.x;
  int d = chain & 1023;
  int b = __builtin_amdgcn_readfirstlane(chain >> 10);
  float Aj[16];
  #pragma unroll
  for (int q = 0; q < 4; q++){
    float4 al = *(const float4*)(A_log + (size_t)d * 16 + q * 4);
    Aj[q*4+0] = -__expf(al.x); Aj[q*4+1] = -__expf(al.y);
    Aj[q*4+2] = -__expf(al.z); Aj[q*4+3] = -__expf(al.w);
  }
  float a0 = Aj[0];
  int lf = 1;
  #pragma unroll
  for (int j = 1; j < 16; j++)
    lf &= (fabsf(Aj[j] - (j + 1) * a0) <= 2e-3f * (j + 1) * fabsf(a0));
  bool wfast = __all(lf);
  float Dpv = Dp[d];

  constexpr ptrdiff_t sBC = DIR ? -32 : 32;
  constexpr ptrdiff_t sX  = DIR ? -1024 : 1024;
  int p0 = seg * L;
  int len = Nn - p0; if (len > L) len = L;
  size_t tok0 = (size_t)b * Nn + (DIR ? (Nn - 1 - p0) : p0);
  const float* lBC = bc  + tok0 * 32;          // wave-uniform
  const f16*   lDt = dty + tok0 * 1024 + d;
  const f16*   lXi = xi  + tok0 * 1024 + d;
  f16*         pY  = dty + tok0 * 1024 + d;

  float h[16];
  if (seg){
    const float* hp = hseg + ((size_t)(seg - 1) * NCH + chain) * 16;
    #pragma unroll
    for (int q = 0; q < 4; q++){
      float4 hl = *(const float4*)(hp + 4*q);
      h[q*4+0] = hl.x; h[q*4+1] = hl.y; h[q*4+2] = hl.z; h[q*4+3] = hl.w;
    }
  } else {
    #pragma unroll
    for (int j = 0; j < 16; j++) h[j] = 0.f;
  }

  float dtA, xvA, dtB, xvB;
  float4 QA[8], QB[8];   // B (0..3) and C (4..7)

  #define LOADP2(dt_r, xv_r, Qq)                                   \
    { dt_r = (float)*lDt; xv_r = (float)*lXi;                      \
      _Pragma("unroll")                                            \
      for (int q = 0; q < 8; q++) Qq[q] = *(const float4*)(lBC + 4*q); \
      lDt += sX; lXi += sX; lBC += sBC; }

  auto run = [&](auto FAST){
    auto stepv = [&](float dt, float xv, const float4* Qq){
      float dtx = dt * xv;
      float B[16] = {Qq[0].x,Qq[0].y,Qq[0].z,Qq[0].w, Qq[1].x,Qq[1].y,Qq[1].z,Qq[1].w,
                     Qq[2].x,Qq[2].y,Qq[2].z,Qq[2].w, Qq[3].x,Qq[3].y,Qq[3].z,Qq[3].w};
      float C[16] = {Qq[4].x,Qq[4].y,Qq[4].z,Qq[4].w, Qq[5].x,Qq[5].y,Qq[5].z,Qq[5].w,
                     Qq[6].x,Qq[6].y,Qq[6].z,Qq[6].w, Qq[7].x,Qq[7].y,Qq[7].z,Qq[7].w};
      float dA[16];
      mk_dA<decltype(FAST)::value>(dt, a0, Aj, dA);
      float yv = xv * Dpv;
      #pragma unroll
      for (int j = 0; j < 16; j++){
        h[j] = fmaf(dA[j], h[j], dtx * B[j]);
        yv = fmaf(h[j], C[j], yv);
      }
      *pY = (f16)yv;
      pY += sX;
    };
    LOADP2(dtA, xvA, QA);
    int t = 0;
    for (; t + 3 <= len; t += 2){
      LOADP2(dtB, xvB, QB);
      asm volatile("" ::: "memory");
      stepv(dtA, xvA, QA);
      LOADP2(dtA, xvA, QA);
      asm volatile("" ::: "memory");
      stepv(dtB, xvB, QB);
    }
    stepv(dtA, xvA, QA); t++;
    if (t < len){ LOADP2(dtB, xvB, QB); stepv(dtB, xvB, QB); }
  };
  if (wfast) run(BoolC<true>{}); else run(BoolC<false>{});
  #undef LOADP2
}

// ---------------- (optional add) + LayerNorm; writes f32 e AND f16 e16 ----------------
__global__ __launch_bounds__(256) void add_ln_kernel(
    float* __restrict__ e, const float* __restrict__ add,
    const float* __restrict__ w, const float* __restrict__ bias,
    f16* __restrict__ e16)
{
  int wv = threadIdx.x >> 6, lane = threadIdx.x & 63;
  int tok = blockIdx.x * 4 + wv;
  float* p = e + (size_t)tok * Dm;
  float4 v0 = ((const float4*)p)[lane * 2];
  float4 v1 = ((const float4*)p)[lane * 2 + 1];
  float x[8] = {v0.x, v0.y, v0.z, v0.w, v1.x, v1.y, v1.z, v1.w};
  if (add){
    const float* q = add + (size_t)tok * Dm;
    float4 a0 = ((const float4*)q)[lane * 2];
    float4 a1 = ((const float4*)q)[lane * 2 + 1];
    x[0] += a0.x; x[1] += a0.y; x[2] += a0.z; x[3] += a0.w;
    x[4] += a1.x; x[5] += a1.y; x[6] += a1.z; x[7] += a1.w;
  }
  float s = 0.f;
  #pragma unroll
  for (int i = 0; i < 8; i++) s += x[i];
  #pragma unroll
  for (int off = 32; off; off >>= 1) s += __shfl_xor(s, off);
  float m = s * (1.f / Dm);
  float vv = 0.f;
  #pragma unroll
  for (int i = 0; i < 8; i++){ float dd = x[i] - m; vv += dd * dd; }
  #pragma unroll
  for (int off = 32; off; off >>= 1) vv += __shfl_xor(vv, off);
  float rs = rsqrtf(vv * (1.f / Dm) + EPSf);
  int db = lane * 8;
  float4 w0 = *(const float4*)(w + db),    w1 = *(const float4*)(w + db + 4);
  float4 b0 = *(const float4*)(bias + db), b1 = *(const float4*)(bias + db + 4);
  float wr[8] = {w0.x, w0.y, w0.z, w0.w, w1.x, w1.y, w1.z, w1.w};
  float br[8] = {b0.x, b0.y, b0.z, b0.w, b1.x, b1.y, b1.z, b1.w};
  float o[8];
  #pragma unroll
  for (int i = 0; i < 8; i++) o[i] = (x[i] - m) * rs * wr[i] + br[i];
  ((float4*)p)[lane * 2]     = make_float4(o[0], o[1], o[2], o[3]);
  ((float4*)p)[lane * 2 + 1] = make_float4(o[4], o[5], o[6], o[7]);
  f16x8 hv;
  #pragma unroll
  for (int i = 0; i < 8; i++) hv[i] = (f16)o[i];
  *(f16x8*)(e16 + (size_t)tok * Dm + db) = hv;
}

// ---------------- de-normalize + transpose to (B, FUT, N) ----------------
__global__ __launch_bounds__(256) void final_kernel(
    const float* __restrict__ dec, const float* __restrict__ meanb,
    const float* __restrict__ stdb, const float* __restrict__ rw,
    const float* __restrict__ rb, float* __restrict__ out)
{
  int idx = blockIdx.x * 256 + threadIdx.x;
  if (idx >= Bb * FUTc * Nn) return;
  int n  = idx % Nn;
  int bf = idx / Nn;
  int f  = bf % FUTc;
  int b  = bf / FUTc;
  int tok = b * Nn + n;
  float v = dec[(size_t)tok * FUTc + f];
  out[idx] = (v - rb[n]) / (rw[n] + 1e-10f) * stdb[tok] + meanb[tok];
}

extern "C" void kernel_launch(void* const* d_in, const int* in_sizes, int n_in,
                              void* d_out, int out_size, void* d_ws, size_t ws_size,
                              hipStream_t stream)
{
  const float* x_hist    = (const float*)d_in[0];
  const float* revin_w   = (const float*)d_in[1];
  const float* revin_b   = (const float*)d_in[2];
  const float* embed_w   = (const float*)d_in[3];
  const float* embed_b   = (const float*)d_in[4];
  const float* in_proj_w = (const float*)d_in[5];
  const float* conv_w    = (const float*)d_in[6];
  const float* conv_b    = (const float*)d_in[7];
  const float* x_proj_w  = (const float*)d_in[8];
  const float* dt_proj_w = (const float*)d_in[9];
  const float* dt_proj_b = (const float*)d_in[10];
  const float* A_log     = (const float*)d_in[11];
  const float* Dp        = (const float*)d_in[12];
  const float* out_proj_w= (const float*)d_in[13];
  const float* conv1_w   = (const float*)d_in[14];
  const float* conv1_b   = (const float*)d_in[15];
  const float* conv2_w   = (const float*)d_in[16];
  const float* conv2_b   = (const float*)d_in[17];
  const float* norm1_w   = (const float*)d_in[18];
  const float* norm1_b   = (const float*)d_in[19];
  const float* norm2_w   = (const float*)d_in[20];
  const float* norm2_b   = (const float*)d_in[21];
  const float* normf_w   = (const float*)d_in[22];
  const float* normf_b   = (const float*)d_in[23];
  const float* proj_w    = (const float*)d_in[24];
  const float* proj_b    = (const float*)d_in[25];

  // ---- workspace layout (~219 MB fixed) ----
  float* ws    = (float*)d_ws;
  float* meanb = ws;                                    // TT f32
  float* stdb  = meanb + TT;                            // TT f32
  float* e     = stdb + TT;                             // TT*512 f32
  f16*   e16   = (f16*)(e + (size_t)TT * Dm);           // TT*512 f16
  f16*   x16   = e16 + (size_t)TT * Dm;                 // TT*1024 f16 (conv in; dt; y)
  f16*   xi16  = x16 + (size_t)TT * Di;                 // TT*1024 f16 (conv out / scan in)
  float* bc32  = (float*)(xi16 + (size_t)TT * Di);      // TT*32 f32 (packed B,C)
  f16*   dt16in= (f16*)(bc32 + (size_t)TT * 32);        // TT*32 f16 (dt_in only)
  f16*   ipw16 = dt16in + (size_t)TT * 32;              // 4*2048*512
  f16*   opw16 = ipw16 + (size_t)4 * 2048 * Dm;         // 4*512*1024
  f16*   c1w16 = opw16 + (size_t)4 * Dm * Di;           // 2*512*512
  f16*   c2w16 = c1w16 + (size_t)2 * Dm * Dm;           // 2*512*512
  f16*   xpw16 = c2w16 + (size_t)2 * Dm * Dm;           // 4*64*1024
  f16*   dtw16 = xpw16 + (size_t)4 * 64 * Di;           // 4*1024*32
  f16*   emw16 = dtw16 + (size_t)4 * Di * DRr;          // 512*96
  f16*   prw16 = emw16 + (size_t)Dm * Lh;               // 96*512
  float* hseg  = (float*)(((uintptr_t)(prw16 + (size_t)FUTc * Dm) + 15) & ~(uintptr_t)15);

  size_t used = (uintptr_t)hseg - (uintptr_t)ws;
  size_t segbytes = ((size_t)NCH * 16 + NCH) * sizeof(float);
  int S = 1;
  if (ws_size > used) S = 1 + (int)((ws_size - used) / segbytes);
  if (S > 8) S = 8;
  if (S < 1) S = 1;
  const int L = (Nn + S - 1) / S;
  float* sdtb = hseg + (size_t)(S > 1 ? S - 1 : 0) * NCH * 16;

  // aliases into freed regions
  f16*   xn16  = x16;               // [TT][96] embed staging (pre-loop)
  f16*   h16   = xi16;              // [TT][512] FFN hidden (post-mamba)
  float* ftmp  = (float*)x16;       // [TT][512] f32 conv2 out
  float* dec   = (float*)x16;       // [TT][96] f32 final projection

  dim3 blk(256);
  auto cvt = [&](const float* in, f16* out, size_t n){
    int n4 = (int)(n / 4);
    cvt_kernel<<<(n4 + 255) / 256, blk, 0, stream>>>(in, out, n4);
  };
  cvt(in_proj_w,  ipw16, (size_t)4 * 2048 * Dm);
  cvt(out_proj_w, opw16, (size_t)4 * Dm * Di);
  cvt(conv1_w,    c1w16, (size_t)2 * Dm * Dm);
  cvt(conv2_w,    c2w16, (size_t)2 * Dm * Dm);
  cvt(x_proj_w,   xpw16, (size_t)4 * 64 * Di);
  cvt(dt_proj_w,  dtw16, (size_t)4 * Di * DRr);
  cvt(embed_w,    emw16, (size_t)Dm * Lh);
  cvt(proj_w,     prw16, (size_t)FUTc * Dm);

  stats_kernel<<<(TT + 255) / 256, blk, 0, stream>>>(x_hist, meanb, stdb);
  prep_kernel<<<(Bb * Lh * Nn + 255) / 256, blk, 0, stream>>>(x_hist, meanb, stdb, revin_w, revin_b, xn16);

  const int gy = (TT + 127) / 128;   // 216
  // embed: [TT,96] x [512,96] -> e (f32) + e16
  gemm16_kernel<0,0,1,1><<<dim3(4, gy), blk, 0, stream>>>(
      xn16, Lh, emw16, Lh, embed_b, e, Dm, e16, Dm, Dm, TT);

  constexpr int NG = (Nn + 7) / 8;   // conv token-groups
  const int convGrid = (Bb * NG * 128 + 255) / 256;

  for (int l = 0; l < 2; l++){
    for (int dir = 0; dir < 2; dir++){
      int wi = l * 2 + dir;
      const f16* Wx = ipw16 + (size_t)wi * 2048 * Dm;           // rows 0..1023 (x half)
      const f16* Wz = Wx + (size_t)Di * Dm;                     // rows 1024..2047 (z half)
      const float* Alw = A_log + (size_t)wi * Di * Ds;
      // in_proj x-half: [TT,512] x [1024,512] -> x16 f16
      gemm16_kernel<0,0,0,1><<<dim3(8, gy), blk, 0, stream>>>(
          e16, Dm, Wx, Dm, nullptr, nullptr, 0, x16, Di, Di, TT);
      // depthwise conv + silu: x16 -> xi16   (x16 dead after this)
      if (dir) conv2_kernel<1><<<convGrid, blk, 0, stream>>>(
                   x16, conv_w + (size_t)wi * Di * 4, conv_b + (size_t)wi * Di, xi16);
      else     conv2_kernel<0><<<convGrid, blk, 0, stream>>>(
                   x16, conv_w + (size_t)wi * Di * 4, conv_b + (size_t)wi * Di, xi16);
      // x_proj (TN=64): [TT,1024] x [64,1024] -> bc32 f32 (o>=32, packed) + dt16in f16 (o<32)
      gemm16_kernel<0,0,1,1,32,32,64><<<dim3(1, gy), blk, 0, stream>>>(
          xi16, Di, xpw16 + (size_t)wi * 64 * Di, Di, nullptr,
          bc32, 32, dt16in, 32, 64, TT);
      // dt_proj + softplus: [TT,32] x [1024,32] -> dt f16 into x16
      gemm16_kernel<2,0,0,1><<<dim3(8, gy), blk, 0, stream>>>(
          dt16in, 32, dtw16 + (size_t)wi * Di * DRr, DRr, dt_proj_b + (size_t)wi * Di,
          nullptr, 0, x16, Di, Di, TT);
      // segmented scan: pass1 + combine + pass2 (y overwrites dt in x16)
      if (S > 1){
        if (dir) scan_p1_kernel<1><<<dim3(NCH / 256, S - 1), blk, 0, stream>>>(
                     bc32, x16, xi16, Alw, hseg, sdtb, L);
        else     scan_p1_kernel<0><<<dim3(NCH / 256, S - 1), blk, 0, stream>>>(
                     bc32, x16, xi16, Alw, hseg, sdtb, L);
        scan_cb_kernel<<<NCH / 256, blk, 0, stream>>>(Alw, hseg, sdtb, S - 1);
      }
      if (dir) scan_p2_kernel<1><<<dim3(NCH / 256, S), blk, 0, stream>>>(
                   bc32, x16, xi16, Alw, Dp + (size_t)wi * Di, hseg, L);
      else     scan_p2_kernel<0><<<dim3(NCH / 256, S), blk, 0, stream>>>(
                   bc32, x16, xi16, Alw, Dp + (size_t)wi * Di, hseg, L);
      // gate: y(x16) *= silu(e16 @ Wz^T)   (f16 RMW epilogue, prefetched)
      gemm16_kernel<3,0,0,1><<<dim3(8, gy), blk, 0, stream>>>(
          e16, Dm, Wz, Dm, nullptr, nullptr, 0, x16, Di, Di, TT);
      // out_proj: [TT,1024] x [512,1024] -> e += (residual accumulate, prefetched)
      gemm16_kernel<0,1,1,0><<<dim3(4, gy), blk, 0, stream>>>(
          x16, Di, opw16 + (size_t)wi * Dm * Di, Di, nullptr,
          e, Dm, nullptr, 0, Dm, TT);
    }
    // e = LN(e) (mf+mr already accumulated); regenerate e16
    add_ln_kernel<<<TT / 4, blk, 0, stream>>>(e, nullptr, norm1_w + l * Dm, norm1_b + l * Dm, e16);
    // FFN: conv1 relu -> h16 (aliases xi16)
    gemm16_kernel<1,0,0,1><<<dim3(4, gy), blk, 0, stream>>>(
        e16, Dm, c1w16 + (size_t)l * Dm * Dm, Dm, conv1_b + l * Dm,
        nullptr, 0, h16, Dm, Dm, TT);
    // conv2 -> ftmp f32 (aliases x16)
    gemm16_kernel<0,0,1,0><<<dim3(4, gy), blk, 0, stream>>>(
        h16, Dm, c2w16 + (size_t)l * Dm * Dm, Dm, conv2_b + l * Dm,
        ftmp, Dm, nullptr, 0, Dm, TT);
    add_ln_kernel<<<TT / 4, blk, 0, stream>>>(e, ftmp, norm2_w + l * Dm, norm2_b + l * Dm, e16);
  }

  add_ln_kernel<<<TT / 4, blk, 0, stream>>>(e, nullptr, normf_w, normf_b, e16);
  // proj: [TT,512] x [96,512] -> dec f32
  gemm16_kernel<0,0,1,0><<<dim3(1, gy), blk, 0, stream>>>(
      e16, Dm, prw16, Dm, proj_b, dec, FUTc, nullptr, 0, FUTc, TT);
  final_kernel<<<(Bb * FUTc * Nn + 255) / 256, blk, 0, stream>>>(
      dec, meanb, stdb, revin_w, revin_b, (float*)d_out);
}

// Round 16
// 2478.016 us; speedup vs baseline: 1.0017x; 1.0017x over previous
//
#include <hip/hip_runtime.h>

// SDMamba forward. All GEMMs on MFMA f16 (fp32 accumulate); conv/scan/LN fp32 math.
// Segmented scan (p1 local+sum(dt), combine, p2 rescan), 1 lane = 1 chain, 16 states
// in-lane; A_log=log(1..16) fast path (one exp + pow-tree). Conv: rolling window.
// GEMM: single-buffer 2-barrier K-loop (round-12 structure; implicit multi-block
// overlap, 16KB LDS -> ~5 blocks/CU) + fragment-order LDS (512 halves/fragment,
// conflict-free ds_read_b128); XCD-chunk swizzle; epilogue RMW prefetch; TN=64
// variant for x_proj.

typedef _Float16 f16;
typedef _Float16 f16x8 __attribute__((ext_vector_type(8)));
typedef _Float16 f16x4 __attribute__((ext_vector_type(4)));
typedef float    f32x4 __attribute__((ext_vector_type(4)));

template<bool B> struct BoolC { static constexpr bool value = B; };

constexpr int Bb  = 32;
constexpr int Lh  = 96;
constexpr int FUTc= 96;
constexpr int Nn  = 862;
constexpr int Dm  = 512;
constexpr int Ds  = 16;
constexpr int Di  = 1024;
constexpr int DRr = 32;
constexpr int TT  = Bb * Nn;     // 27584
constexpr int NCH = Bb * Di;     // 32768 scan chains
constexpr float EPSf = 1e-5f;

__device__ __forceinline__ float sigm(float x){ return 1.f / (1.f + __expf(-x)); }

__device__ __forceinline__ void gll16(f16* lds, const f16* g){
  __builtin_amdgcn_global_load_lds(
      (const __attribute__((address_space(1))) void*)g,
      (__attribute__((address_space(3)))       void*)lds, 16, 0, 0);
}

// ---------------- RevIN stats ----------------
__global__ __launch_bounds__(256) void stats_kernel(const float* __restrict__ x,
    float* __restrict__ meanb, float* __restrict__ stdb)
{
  int i = blockIdx.x * 256 + threadIdx.x;
  if (i >= TT) return;
  int b = i / Nn, n = i - b * Nn;
  const float* p = x + (size_t)b * Lh * Nn + n;
  float s = 0.f, sq = 0.f;
  #pragma unroll 4
  for (int l = 0; l < Lh; l++){ float v = p[(size_t)l * Nn]; s += v; sq += v * v; }
  float m = s * (1.f / Lh);
  float var = sq * (1.f / Lh) - m * m;
  meanb[i] = m;
  stdb[i]  = sqrtf(var + EPSf);
}

// ---------------- normalize + layout to [tok][L] fp16 ----------------
__global__ __launch_bounds__(256) void prep_kernel(const float* __restrict__ x,
    const float* __restrict__ meanb, const float* __restrict__ stdb,
    const float* __restrict__ rw, const float* __restrict__ rb,
    f16* __restrict__ xn16)
{
  int idx = blockIdx.x * 256 + threadIdx.x;
  if (idx >= Bb * Lh * Nn) return;
  int n  = idx % Nn;
  int bl = idx / Nn;
  int l  = bl % Lh;
  int b  = bl / Lh;
  int tok = b * Nn + n;
  float v = x[idx];
  xn16[(size_t)tok * Lh + l] = (f16)((v - meanb[tok]) / stdb[tok] * rw[n] + rb[n]);
}

// ---------------- f32 -> f16 convert ----------------
__global__ __launch_bounds__(256) void cvt_kernel(const float* __restrict__ in,
    f16* __restrict__ out, int n4)
{
  int i = blockIdx.x * 256 + threadIdx.x;
  if (i >= n4) return;
  float4 v = ((const float4*)in)[i];
  f16x4 h; h[0] = (f16)v.x; h[1] = (f16)v.y; h[2] = (f16)v.z; h[3] = (f16)v.w;
  *(f16x4*)(out + (size_t)i * 4) = h;
}

// ---------------- MFMA GEMM: C[m,o] = act(sum_k A[m,k]*W[o,k] + bias[o]) ----------------
// ACT: 0 none, 1 relu, 2 softplus (fast), 3 silu-gate-RMW on C16 (C16 *= silu(v)).
// ACC: C += (W32 path). W32/W16: write f32 C / f16 C16.
// OMIN: f32 write only for o>=OMIN at col (o-OMIN). OMAX16: f16 write only for o<OMAX16.
// TN: tile width (128 or 64).
// LDS is FRAGMENT-ORDER: fragment fr (16 rows x 32 halves = 512 halves) at base
// fr*512, lane l = (kchunk<<4)|row holds 8 halves at fragbase + l*8. Staged by
// permuting the per-lane GLOBAL source (gll16 dest = base + lane*16B always).
template<int ACT, int ACC, int W32, int W16, int OMIN = 0, int OMAX16 = (1 << 30), int TN = 128>
__global__ __launch_bounds__(256) void gemm16_kernel(
    const f16* __restrict__ A, int lda,
    const f16* __restrict__ W, int K,
    const float* __restrict__ bias,
    float* __restrict__ C, int ldc,
    f16* __restrict__ C16, int ldc16,
    int O, int M)
{
  constexpr int JN = (TN == 64) ? 2 : 4;
  __shared__ f16 As[128 * 32];
  __shared__ f16 Bs[TN * 32];
  const int tid  = threadIdx.x;
  const int lane = tid & 63;
  const int w    = tid >> 6;
  const int wm   = w >> 1, wn = w & 1;
  // XCD-chunk swizzle (bijective, any nwg)
  int bid = blockIdx.y * gridDim.x + blockIdx.x;
  int nwg = gridDim.x * gridDim.y;
  int q = nwg >> 3, r = nwg & 7;
  int xcd = bid & 7, idx = bid >> 3;
  int swz = (xcd < r ? xcd * (q + 1) : r * (q + 1) + (xcd - r) * q) + idx;
  const int m0   = (swz / gridDim.x) * 128, o0 = (swz % gridDim.x) * TN;
  const int wmM  = wm * 64;
  const int wnN  = (TN == 64) ? wn * 32 : wn * 64;
  const int lm   = lane & 15, kg = lane >> 4;
  const int lm16 = lane & 15, kch = lane >> 4;   // staging: row-in-frag, k-chunk

  f32x4 acc[4][JN];
  #pragma unroll
  for (int i = 0; i < 4; i++)
    #pragma unroll
    for (int j = 0; j < JN; j++){ f32x4 z = {0.f,0.f,0.f,0.f}; acc[i][j] = z; }

  for (int k0 = 0; k0 < K; k0 += 32){
    __syncthreads();
    {
      int fr0 = 2 * w;                         // this wave's two A fragments
      int r0 = min(m0 + fr0 * 16 + lm16,      M - 1);
      int r1 = min(m0 + fr0 * 16 + 16 + lm16, M - 1);
      gll16(&As[(size_t)fr0 * 512],       A + (size_t)r0 * lda + k0 + kch * 8);
      gll16(&As[(size_t)fr0 * 512 + 512], A + (size_t)r1 * lda + k0 + kch * 8);
      if constexpr (TN == 128){
        int q0 = min(o0 + fr0 * 16 + lm16,      O - 1);
        int q1 = min(o0 + fr0 * 16 + 16 + lm16, O - 1);
        gll16(&Bs[(size_t)fr0 * 512],       W + (size_t)q0 * K + k0 + kch * 8);
        gll16(&Bs[(size_t)fr0 * 512 + 512], W + (size_t)q1 * K + k0 + kch * 8);
      } else {
        int q0 = min(o0 + w * 16 + lm16, O - 1);
        gll16(&Bs[(size_t)w * 512], W + (size_t)q0 * K + k0 + kch * 8);
      }
    }
    __syncthreads();
    f16x8 af[4], bf[JN];
    #pragma unroll
    for (int f = 0; f < 4; f++)
      af[f] = *(const f16x8*)&As[(size_t)(wm * 4 + f) * 512 + lane * 8];
    #pragma unroll
    for (int f = 0; f < JN; f++)
      bf[f] = *(const f16x8*)&Bs[(size_t)((TN == 64 ? wn * 2 : wn * 4) + f) * 512 + lane * 8];
    #pragma unroll
    for (int i = 0; i < 4; i++)
      #pragma unroll
      for (int j = 0; j < JN; j++)
        acc[i][j] = __builtin_amdgcn_mfma_f32_16x16x32_f16(af[i], bf[j], acc[i][j], 0, 0, 0);
  }

  // ---- epilogue with i-sliced RMW prefetch (ACT3: f16; ACC: f32) ----
  f16   pf16[2][4][JN];
  float pf32[2][4][JN];
  auto ldslice = [&](int i, int bank){
    if constexpr (ACT == 3){
      #pragma unroll
      for (int r2 = 0; r2 < 4; r2++){
        int m = min(m0 + wmM + i * 16 + kg * 4 + r2, M - 1);
        #pragma unroll
        for (int j = 0; j < JN; j++){
          int o = min(o0 + wnN + j * 16 + lm, O - 1);
          pf16[bank][r2][j] = C16[(size_t)m * ldc16 + o];
        }
      }
    }
    if constexpr (ACC == 1){
      #pragma unroll
      for (int r2 = 0; r2 < 4; r2++){
        int m = min(m0 + wmM + i * 16 + kg * 4 + r2, M - 1);
        #pragma unroll
        for (int j = 0; j < JN; j++){
          int o = min(o0 + wnN + j * 16 + lm, O - 1);
          if (o >= OMIN) pf32[bank][r2][j] = C[(size_t)m * ldc + (o - OMIN)];
        }
      }
    }
  };
  ldslice(0, 0);
  #pragma unroll
  for (int i = 0; i < 4; i++){
    if (i < 3) ldslice(i + 1, (i + 1) & 1);
    #pragma unroll
    for (int r2 = 0; r2 < 4; r2++){
      int m = m0 + wmM + i * 16 + kg * 4 + r2;
      if (m >= M) continue;
      #pragma unroll
      for (int j = 0; j < JN; j++){
        int o = o0 + wnN + j * 16 + lm;
        if (o >= O) continue;
        float v = acc[i][j][r2];
        if (bias) v += bias[o];
        if (ACT == 1) v = fmaxf(v, 0.f);
        if (ACT == 2) v = fmaxf(v, 0.f) + __logf(1.f + __expf(-fabsf(v)));
        if (ACT == 3){
          float gate = v * sigm(v);
          C16[(size_t)m * ldc16 + o] = (f16)((float)pf16[i & 1][r2][j] * gate);
        } else {
          if (W32 && o >= OMIN){
            if (ACC) v += pf32[i & 1][r2][j];
            C[(size_t)m * ldc + (o - OMIN)] = v;
          }
          if (W16 && o < OMAX16) C16[(size_t)m * ldc16 + o] = (f16)v;
        }
      }
    }
  }
}

// ---------------- depthwise causal conv (len 4) + SiLU ----------------
// 8 tokens x 8 channels per thread, rolling 4-row register window.
template<int DIR>
__global__ __launch_bounds__(256) void conv2_kernel(
    const f16* __restrict__ x16, const float* __restrict__ w,
    const float* __restrict__ cb, f16* __restrict__ xi16)
{
  constexpr int TG = 8;
  constexpr int NG = (Nn + TG - 1) / TG;       // 108 token-groups
  int idx = blockIdx.x * 256 + threadIdx.x;
  if (idx >= Bb * NG * 128) return;
  int d8 = (idx & 127) << 3;
  int gg = idx >> 7;
  int g  = gg % NG, b = gg / NG;
  int n0 = g * TG;
  const f16* base  = x16  + (size_t)b * Nn * 1024 + d8;
  f16*       obase = xi16 + (size_t)b * Nn * 1024 + d8;

  float bias[8];
  {
    float4 c0 = *(const float4*)(cb + d8), c1 = *(const float4*)(cb + d8 + 4);
    bias[0]=c0.x; bias[1]=c0.y; bias[2]=c0.z; bias[3]=c0.w;
    bias[4]=c1.x; bias[5]=c1.y; bias[6]=c1.z; bias[7]=c1.w;
  }
  float wr[4][8];
  #pragma unroll
  for (int i = 0; i < 8; i++){
    float4 wv = *(const float4*)(w + (size_t)(d8 + i) * 4);
    wr[0][i]=wv.x; wr[1][i]=wv.y; wr[2][i]=wv.z; wr[3][i]=wv.w;
  }

  f16x8 zv;
  #pragma unroll
  for (int i = 0; i < 8; i++) zv[i] = (f16)0.f;

  f16x8 win[4];
  #pragma unroll
  for (int j = 0; j < 3; j++){
    int r = DIR ? (n0 + j) : (n0 - 3 + j);
    bool ok = DIR ? (r < Nn) : (r >= 0);
    win[j] = ok ? *(const f16x8*)(base + (size_t)r * 1024) : zv;
  }
  #pragma unroll
  for (int s = 0; s < TG; s++){
    int n = n0 + s;
    if (n < Nn){
      int r = DIR ? (n + 3) : n;
      bool ok = DIR ? (r < Nn) : true;
      win[3] = ok ? *(const f16x8*)(base + (size_t)r * 1024) : zv;
      float acc[8];
      #pragma unroll
      for (int i = 0; i < 8; i++) acc[i] = bias[i];
      #pragma unroll
      for (int k = 0; k < 4; k++){
        const f16x8& rv = DIR ? win[3 - k] : win[k];
        #pragma unroll
        for (int i = 0; i < 8; i++) acc[i] = fmaf(wr[k][i], (float)rv[i], acc[i]);
      }
      f16x8 o;
      #pragma unroll
      for (int i = 0; i < 8; i++){ float a = acc[i]; o[i] = (f16)(a * sigm(a)); }
      *(f16x8*)(obase + (size_t)n * 1024) = o;
      win[0] = win[1]; win[1] = win[2]; win[2] = win[3];
    }
  }
}

// dA[j] = p^(j+1) for j=0..15 from one exp (tree, depth 4)
__device__ __forceinline__ void pow16(float pp, float* dA){
  float q2 = pp * pp, q3 = q2 * pp, q4 = q2 * q2, q8 = q4 * q4;
  dA[0] = pp;      dA[1] = q2;      dA[2] = q3;      dA[3] = q4;
  dA[4] = q4 * pp; dA[5] = q4 * q2; dA[6] = q4 * q3; dA[7] = q8;
  dA[8] = q8 * pp; dA[9] = q8 * q2; dA[10]= q8 * q3; dA[11]= q8 * q4;
  dA[12]= q8 * dA[4]; dA[13]= q8 * dA[5]; dA[14]= q8 * dA[6]; dA[15]= q8 * q8;
}

template<bool FAST>
__device__ __forceinline__ void mk_dA(float dt, float a0, const float* Aj, float* dA){
  if constexpr (FAST){
    pow16(__expf(dt * a0), dA);
  } else {
    _Pragma("unroll")
    for (int j = 0; j < 16; j++) dA[j] = __expf(dt * Aj[j]);
  }
}

// ---------------- scan pass 1: local h + sum(dt) per segment ----------------
template<int DIR>
__global__ __launch_bounds__(256, 2) void scan_p1_kernel(
    const float* __restrict__ bc, const f16* __restrict__ dt_,
    const f16* __restrict__ xi, const float* __restrict__ A_log,
    float* __restrict__ hseg, float* __restrict__ sdt, int L)
{
  const int seg = blockIdx.y;
  int chain = blockIdx.x * 256 + threadIdx.x;
  int d = chain & 1023;
  int b = __builtin_amdgcn_readfirstlane(chain >> 10);   // wave-uniform (256-aligned blocks)
  float Aj[16];
  #pragma unroll
  for (int q = 0; q < 4; q++){
    float4 al = *(const float4*)(A_log + (size_t)d * 16 + q * 4);
    Aj[q*4+0] = -__expf(al.x); Aj[q*4+1] = -__expf(al.y);
    Aj[q*4+2] = -__expf(al.z); Aj[q*4+3] = -__expf(al.w);
  }
  float a0 = Aj[0];
  int lf = 1;
  #pragma unroll
  for (int j = 1; j < 16; j++)
    lf &= (fabsf(Aj[j] - (j + 1) * a0) <= 2e-3f * (j + 1) * fabsf(a0));
  bool wfast = __all(lf);

  constexpr ptrdiff_t sBC = DIR ? -32 : 32;
  constexpr ptrdiff_t sX  = DIR ? -1024 : 1024;
  int p0 = seg * L;
  size_t tok0 = (size_t)b * Nn + (DIR ? (Nn - 1 - p0) : p0);
  const float* lBC = bc  + tok0 * 32;          // wave-uniform -> scalar loads
  const f16*   lDt = dt_ + tok0 * 1024 + d;
  const f16*   lXi = xi  + tok0 * 1024 + d;

  float h[16];
  #pragma unroll
  for (int j = 0; j < 16; j++) h[j] = 0.f;
  float sacc = 0.f;

  float dtA, xvA, dtB, xvB;
  float4 BA[4], BB[4];

  #define LOADP1(dt_r, xv_r, Bq)                                   \
    { dt_r = (float)*lDt; xv_r = (float)*lXi;                      \
      _Pragma("unroll")                                            \
      for (int q = 0; q < 4; q++) Bq[q] = *(const float4*)(lBC + 4*q); \
      lDt += sX; lXi += sX; lBC += sBC; }

  auto run = [&](auto FAST){
    auto stepv = [&](float dt, float xv, const float4* Bq){
      sacc += dt;
      float dtx = dt * xv;
      float B[16] = {Bq[0].x,Bq[0].y,Bq[0].z,Bq[0].w, Bq[1].x,Bq[1].y,Bq[1].z,Bq[1].w,
                     Bq[2].x,Bq[2].y,Bq[2].z,Bq[2].w, Bq[3].x,Bq[3].y,Bq[3].z,Bq[3].w};
      float dA[16];
      mk_dA<decltype(FAST)::value>(dt, a0, Aj, dA);
      #pragma unroll
      for (int j = 0; j < 16; j++)
        h[j] = fmaf(dA[j], h[j], dtx * B[j]);
    };
    LOADP1(dtA, xvA, BA);
    int t = 0;
    for (; t + 3 <= L; t += 2){
      LOADP1(dtB, xvB, BB);
      asm volatile("" ::: "memory");
      stepv(dtA, xvA, BA);
      LOADP1(dtA, xvA, BA);
      asm volatile("" ::: "memory");
      stepv(dtB, xvB, BB);
    }
    stepv(dtA, xvA, BA); t++;
    if (t < L){ LOADP1(dtB, xvB, BB); stepv(dtB, xvB, BB); }
  };
  if (wfast) run(BoolC<true>{}); else run(BoolC<false>{});
  #undef LOADP1

  float* hp = hseg + ((size_t)seg * NCH + chain) * 16;
  #pragma unroll
  for (int q = 0; q < 4; q++)
    *(float4*)(hp + 4*q) = make_float4(h[q*4], h[q*4+1], h[q*4+2], h[q*4+3]);
  sdt[(size_t)seg * NCH + chain] = sacc;
}

// ---------------- scan combine: hseg[s] := h_in(seg s+1), in place ----------------
__global__ __launch_bounds__(256) void scan_cb_kernel(
    const float* __restrict__ A_log, float* __restrict__ hseg,
    const float* __restrict__ sdt, int Sm1)
{
  int chain = blockIdx.x * 256 + threadIdx.x;
  int d = chain & 1023;
  float Aj[16];
  #pragma unroll
  for (int q = 0; q < 4; q++){
    float4 al = *(const float4*)(A_log + (size_t)d * 16 + q * 4);
    Aj[q*4+0] = -__expf(al.x); Aj[q*4+1] = -__expf(al.y);
    Aj[q*4+2] = -__expf(al.z); Aj[q*4+3] = -__expf(al.w);
  }
  float tacc[16];
  #pragma unroll
  for (int j = 0; j < 16; j++) tacc[j] = 0.f;
  for (int s = 0; s < Sm1; s++){
    float sd = sdt[(size_t)s * NCH + chain];
    float* hp = hseg + ((size_t)s * NCH + chain) * 16;
    #pragma unroll
    for (int q = 0; q < 4; q++){
      float4 hl = *(const float4*)(hp + 4*q);
      tacc[q*4+0] = fmaf(__expf(Aj[q*4+0] * sd), tacc[q*4+0], hl.x);
      tacc[q*4+1] = fmaf(__expf(Aj[q*4+1] * sd), tacc[q*4+1], hl.y);
      tacc[q*4+2] = fmaf(__expf(Aj[q*4+2] * sd), tacc[q*4+2], hl.z);
      tacc[q*4+3] = fmaf(__expf(Aj[q*4+3] * sd), tacc[q*4+3], hl.w);
      *(float4*)(hp + 4*q) = make_float4(tacc[q*4], tacc[q*4+1], tacc[q*4+2], tacc[q*4+3]);
    }
  }
}

// ---------------- scan pass 2: full rescan per segment, y over dt in place ----------------
template<int DIR>
__global__ __launch_bounds__(256, 2) void scan_p2_kernel(
    const float* __restrict__ bc, f16* dty, const f16* __restrict__ xi,
    const float* __restrict__ A_log, const float* __restrict__ Dp,
    const float* __restrict__ hseg, int L)
{
  const int seg = blockIdx.y;
  int chain = blockIdx.x * 256 + threadIdx.x;
  int d = chain & 1023;
  int b = __builtin_amdgcn_readfirstlane(chain >> 10);
  float Aj[16];
  #pragma unroll
  for (int q = 0; q < 4; q++){
    float4 al = *(const float4*)(A_log + (size_t)d * 16 + q * 4);
    Aj[q*4+0] = -__expf(al.x); Aj[q*4+1] = -__expf(al.y);
    Aj[q*4+2] = -__expf(al.z); Aj[q*4+3] = -__expf(al.w);
  }
  float a0 = Aj[0];
  int lf = 1;
  #pragma unroll
  for (int j = 1; j < 16; j++)
    lf &= (fabsf(Aj[j] - (j + 1) * a0) <= 2e-3f * (j + 1) * fabsf(a0));
  bool wfast = __all(lf);
  float Dpv = Dp[d];

  constexpr ptrdiff_t sBC = DIR ? -32 : 32;
  constexpr ptrdiff_t sX  = DIR ? -1024 : 1024;
  int p0 = seg * L;
  int len = Nn - p0; if (len > L) len = L;
  size_t tok0 = (size_t)b * Nn + (DIR ? (Nn - 1 - p0) : p0);
  const float* lBC = bc  + tok0 * 32;          // wave-uniform
  const f16*   lDt = dty + tok0 * 1024 + d;
  const f16*   lXi = xi  + tok0 * 1024 + d;
  f16*         pY  = dty + tok0 * 1024 + d;

  float h[16];
  if (seg){
    const float* hp = hseg + ((size_t)(seg - 1) * NCH + chain) * 16;
    #pragma unroll
    for (int q = 0; q < 4; q++){
      float4 hl = *(const float4*)(hp + 4*q);
      h[q*4+0] = hl.x; h[q*4+1] = hl.y; h[q*4+2] = hl.z; h[q*4+3] = hl.w;
    }
  } else {
    #pragma unroll
    for (int j = 0; j < 16; j++) h[j] = 0.f;
  }

  float dtA, xvA, dtB, xvB;
  float4 QA[8], QB[8];   // B (0..3) and C (4..7)

  #define LOADP2(dt_r, xv_r, Qq)                                   \
    { dt_r = (float)*lDt; xv_r = (float)*lXi;                      \
      _Pragma("unroll")                                            \
      for (int q = 0; q < 8; q++) Qq[q] = *(const float4*)(lBC + 4*q); \
      lDt += sX; lXi += sX; lBC += sBC; }

  auto run = [&](auto FAST){
    auto stepv = [&](float dt, float xv, const float4* Qq){
      float dtx = dt * xv;
      float B[16] = {Qq[0].x,Qq[0].y,Qq[0].z,Qq[0].w, Qq[1].x,Qq[1].y,Qq[1].z,Qq[1].w,
                     Qq[2].x,Qq[2].y,Qq[2].z,Qq[2].w, Qq[3].x,Qq[3].y,Qq[3].z,Qq[3].w};
      float C[16] = {Qq[4].x,Qq[4].y,Qq[4].z,Qq[4].w, Qq[5].x,Qq[5].y,Qq[5].z,Qq[5].w,
                     Qq[6].x,Qq[6].y,Qq[6].z,Qq[6].w, Qq[7].x,Qq[7].y,Qq[7].z,Qq[7].w};
      float dA[16];
      mk_dA<decltype(FAST)::value>(dt, a0, Aj, dA);
      float yv = xv * Dpv;
      #pragma unroll
      for (int j = 0; j < 16; j++){
        h[j] = fmaf(dA[j], h[j], dtx * B[j]);
        yv = fmaf(h[j], C[j], yv);
      }
      *pY = (f16)yv;
      pY += sX;
    };
    LOADP2(dtA, xvA, QA);
    int t = 0;
    for (; t + 3 <= len; t += 2){
      LOADP2(dtB, xvB, QB);
      asm volatile("" ::: "memory");
      stepv(dtA, xvA, QA);
      LOADP2(dtA, xvA, QA);
      asm volatile("" ::: "memory");
      stepv(dtB, xvB, QB);
    }
    stepv(dtA, xvA, QA); t++;
    if (t < len){ LOADP2(dtB, xvB, QB); stepv(dtB, xvB, QB); }
  };
  if (wfast) run(BoolC<true>{}); else run(BoolC<false>{});
  #undef LOADP2
}

// ---------------- (optional add) + LayerNorm; writes f32 e AND f16 e16 ----------------
__global__ __launch_bounds__(256) void add_ln_kernel(
    float* __restrict__ e, const float* __restrict__ add,
    const float* __restrict__ w, const float* __restrict__ bias,
    f16* __restrict__ e16)
{
  int wv = threadIdx.x >> 6, lane = threadIdx.x & 63;
  int tok = blockIdx.x * 4 + wv;
  float* p = e + (size_t)tok * Dm;
  float4 v0 = ((const float4*)p)[lane * 2];
  float4 v1 = ((const float4*)p)[lane * 2 + 1];
  float x[8] = {v0.x, v0.y, v0.z, v0.w, v1.x, v1.y, v1.z, v1.w};
  if (add){
    const float* q = add + (size_t)tok * Dm;
    float4 a0 = ((const float4*)q)[lane * 2];
    float4 a1 = ((const float4*)q)[lane * 2 + 1];
    x[0] += a0.x; x[1] += a0.y; x[2] += a0.z; x[3] += a0.w;
    x[4] += a1.x; x[5] += a1.y; x[6] += a1.z; x[7] += a1.w;
  }
  float s = 0.f;
  #pragma unroll
  for (int i = 0; i < 8; i++) s += x[i];
  #pragma unroll
  for (int off = 32; off; off >>= 1) s += __shfl_xor(s, off);
  float m = s * (1.f / Dm);
  float vv = 0.f;
  #pragma unroll
  for (int i = 0; i < 8; i++){ float dd = x[i] - m; vv += dd * dd; }
  #pragma unroll
  for (int off = 32; off; off >>= 1) vv += __shfl_xor(vv, off);
  float rs = rsqrtf(vv * (1.f / Dm) + EPSf);
  int db = lane * 8;
  float4 w0 = *(const float4*)(w + db),    w1 = *(const float4*)(w + db + 4);
  float4 b0 = *(const float4*)(bias + db), b1 = *(const float4*)(bias + db + 4);
  float wr[8] = {w0.x, w0.y, w0.z, w0.w, w1.x, w1.y, w1.z, w1.w};
  float br[8] = {b0.x, b0.y, b0.z, b0.w, b1.x, b1.y, b1.z, b1.w};
  float o[8];
  #pragma unroll
  for (int i = 0; i < 8; i++) o[i] = (x[i] - m) * rs * wr[i] + br[i];
  ((float4*)p)[lane * 2]     = make_float4(o[0], o[1], o[2], o[3]);
  ((float4*)p)[lane * 2 + 1] = make_float4(o[4], o[5], o[6], o[7]);
  f16x8 hv;
  #pragma unroll
  for (int i = 0; i < 8; i++) hv[i] = (f16)o[i];
  *(f16x8*)(e16 + (size_t)tok * Dm + db) = hv;
}

// ---------------- de-normalize + transpose to (B, FUT, N) ----------------
__global__ __launch_bounds__(256) void final_kernel(
    const float* __restrict__ dec, const float* __restrict__ meanb,
    const float* __restrict__ stdb, const float* __restrict__ rw,
    const float* __restrict__ rb, float* __restrict__ out)
{
  int idx = blockIdx.x * 256 + threadIdx.x;
  if (idx >= Bb * FUTc * Nn) return;
  int n  = idx % Nn;
  int bf = idx / Nn;
  int f  = bf % FUTc;
  int b  = bf / FUTc;
  int tok = b * Nn + n;
  float v = dec[(size_t)tok * FUTc + f];
  out[idx] = (v - rb[n]) / (rw[n] + 1e-10f) * stdb[tok] + meanb[tok];
}

extern "C" void kernel_launch(void* const* d_in, const int* in_sizes, int n_in,
                              void* d_out, int out_size, void* d_ws, size_t ws_size,
                              hipStream_t stream)
{
  const float* x_hist    = (const float*)d_in[0];
  const float* revin_w   = (const float*)d_in[1];
  const float* revin_b   = (const float*)d_in[2];
  const float* embed_w   = (const float*)d_in[3];
  const float* embed_b   = (const float*)d_in[4];
  const float* in_proj_w = (const float*)d_in[5];
  const float* conv_w    = (const float*)d_in[6];
  const float* conv_b    = (const float*)d_in[7];
  const float* x_proj_w  = (const float*)d_in[8];
  const float* dt_proj_w = (const float*)d_in[9];
  const float* dt_proj_b = (const float*)d_in[10];
  const float* A_log     = (const float*)d_in[11];
  const float* Dp        = (const float*)d_in[12];
  const float* out_proj_w= (const float*)d_in[13];
  const float* conv1_w   = (const float*)d_in[14];
  const float* conv1_b   = (const float*)d_in[15];
  const float* conv2_w   = (const float*)d_in[16];
  const float* conv2_b   = (const float*)d_in[17];
  const float* norm1_w   = (const float*)d_in[18];
  const float* norm1_b   = (const float*)d_in[19];
  const float* norm2_w   = (const float*)d_in[20];
  const float* norm2_b   = (const float*)d_in[21];
  const float* normf_w   = (const float*)d_in[22];
  const float* normf_b   = (const float*)d_in[23];
  const float* proj_w    = (const float*)d_in[24];
  const float* proj_b    = (const float*)d_in[25];

  // ---- workspace layout (~219 MB fixed) ----
  float* ws    = (float*)d_ws;
  float* meanb = ws;                                    // TT f32
  float* stdb  = meanb + TT;                            // TT f32
  float* e     = stdb + TT;                             // TT*512 f32
  f16*   e16   = (f16*)(e + (size_t)TT * Dm);           // TT*512 f16
  f16*   x16   = e16 + (size_t)TT * Dm;                 // TT*1024 f16 (conv in; dt; y)
  f16*   xi16  = x16 + (size_t)TT * Di;                 // TT*1024 f16 (conv out / scan in)
  float* bc32  = (float*)(xi16 + (size_t)TT * Di);      // TT*32 f32 (packed B,C)
  f16*   dt16in= (f16*)(bc32 + (size_t)TT * 32);        // TT*32 f16 (dt_in only)
  f16*   ipw16 = dt16in + (size_t)TT * 32;              // 4*2048*512
  f16*   opw16 = ipw16 + (size_t)4 * 2048 * Dm;         // 4*512*1024
  f16*   c1w16 = opw16 + (size_t)4 * Dm * Di;           // 2*512*512
  f16*   c2w16 = c1w16 + (size_t)2 * Dm * Dm;           // 2*512*512
  f16*   xpw16 = c2w16 + (size_t)2 * Dm * Dm;           // 4*64*1024
  f16*   dtw16 = xpw16 + (size_t)4 * 64 * Di;           // 4*1024*32
  f16*   emw16 = dtw16 + (size_t)4 * Di * DRr;          // 512*96
  f16*   prw16 = emw16 + (size_t)Dm * Lh;               // 96*512
  float* hseg  = (float*)(((uintptr_t)(prw16 + (size_t)FUTc * Dm) + 15) & ~(uintptr_t)15);

  size_t used = (uintptr_t)hseg - (uintptr_t)ws;
  size_t segbytes = ((size_t)NCH * 16 + NCH) * sizeof(float);
  int S = 1;
  if (ws_size > used) S = 1 + (int)((ws_size - used) / segbytes);
  if (S > 8) S = 8;
  if (S < 1) S = 1;
  const int L = (Nn + S - 1) / S;
  float* sdtb = hseg + (size_t)(S > 1 ? S - 1 : 0) * NCH * 16;

  // aliases into freed regions
  f16*   xn16  = x16;               // [TT][96] embed staging (pre-loop)
  f16*   h16   = xi16;              // [TT][512] FFN hidden (post-mamba)
  float* ftmp  = (float*)x16;       // [TT][512] f32 conv2 out
  float* dec   = (float*)x16;       // [TT][96] f32 final projection

  dim3 blk(256);
  auto cvt = [&](const float* in, f16* out, size_t n){
    int n4 = (int)(n / 4);
    cvt_kernel<<<(n4 + 255) / 256, blk, 0, stream>>>(in, out, n4);
  };
  cvt(in_proj_w,  ipw16, (size_t)4 * 2048 * Dm);
  cvt(out_proj_w, opw16, (size_t)4 * Dm * Di);
  cvt(conv1_w,    c1w16, (size_t)2 * Dm * Dm);
  cvt(conv2_w,    c2w16, (size_t)2 * Dm * Dm);
  cvt(x_proj_w,   xpw16, (size_t)4 * 64 * Di);
  cvt(dt_proj_w,  dtw16, (size_t)4 * Di * DRr);
  cvt(embed_w,    emw16, (size_t)Dm * Lh);
  cvt(proj_w,     prw16, (size_t)FUTc * Dm);

  stats_kernel<<<(TT + 255) / 256, blk, 0, stream>>>(x_hist, meanb, stdb);
  prep_kernel<<<(Bb * Lh * Nn + 255) / 256, blk, 0, stream>>>(x_hist, meanb, stdb, revin_w, revin_b, xn16);

  const int gy = (TT + 127) / 128;   // 216
  // embed: [TT,96] x [512,96] -> e (f32) + e16
  gemm16_kernel<0,0,1,1><<<dim3(4, gy), blk, 0, stream>>>(
      xn16, Lh, emw16, Lh, embed_b, e, Dm, e16, Dm, Dm, TT);

  constexpr int NG = (Nn + 7) / 8;   // conv token-groups
  const int convGrid = (Bb * NG * 128 + 255) / 256;

  for (int l = 0; l < 2; l++){
    for (int dir = 0; dir < 2; dir++){
      int wi = l * 2 + dir;
      const f16* Wx = ipw16 + (size_t)wi * 2048 * Dm;           // rows 0..1023 (x half)
      const f16* Wz = Wx + (size_t)Di * Dm;                     // rows 1024..2047 (z half)
      const float* Alw = A_log + (size_t)wi * Di * Ds;
      // in_proj x-half: [TT,512] x [1024,512] -> x16 f16
      gemm16_kernel<0,0,0,1><<<dim3(8, gy), blk, 0, stream>>>(
          e16, Dm, Wx, Dm, nullptr, nullptr, 0, x16, Di, Di, TT);
      // depthwise conv + silu: x16 -> xi16   (x16 dead after this)
      if (dir) conv2_kernel<1><<<convGrid, blk, 0, stream>>>(
                   x16, conv_w + (size_t)wi * Di * 4, conv_b + (size_t)wi * Di, xi16);
      else     conv2_kernel<0><<<convGrid, blk, 0, stream>>>(
                   x16, conv_w + (size_t)wi * Di * 4, conv_b + (size_t)wi * Di, xi16);
      // x_proj (TN=64): [TT,1024] x [64,1024] -> bc32 f32 (o>=32, packed) + dt16in f16 (o<32)
      gemm16_kernel<0,0,1,1,32,32,64><<<dim3(1, gy), blk, 0, stream>>>(
          xi16, Di, xpw16 + (size_t)wi * 64 * Di, Di, nullptr,
          bc32, 32, dt16in, 32, 64, TT);
      // dt_proj + softplus: [TT,32] x [1024,32] -> dt f16 into x16
      gemm16_kernel<2,0,0,1><<<dim3(8, gy), blk, 0, stream>>>(
          dt16in, 32, dtw16 + (size_t)wi * Di * DRr, DRr, dt_proj_b + (size_t)wi * Di,
          nullptr, 0, x16, Di, Di, TT);
      // segmented scan: pass1 + combine + pass2 (y overwrites dt in x16)
      if (S > 1){
        if (dir) scan_p1_kernel<1><<<dim3(NCH / 256, S - 1), blk, 0, stream>>>(
                     bc32, x16, xi16, Alw, hseg, sdtb, L);
        else     scan_p1_kernel<0><<<dim3(NCH / 256, S - 1), blk, 0, stream>>>(
                     bc32, x16, xi16, Alw, hseg, sdtb, L);
        scan_cb_kernel<<<NCH / 256, blk, 0, stream>>>(Alw, hseg, sdtb, S - 1);
      }
      if (dir) scan_p2_kernel<1><<<dim3(NCH / 256, S), blk, 0, stream>>>(
                   bc32, x16, xi16, Alw, Dp + (size_t)wi * Di, hseg, L);
      else     scan_p2_kernel<0><<<dim3(NCH / 256, S), blk, 0, stream>>>(
                   bc32, x16, xi16, Alw, Dp + (size_t)wi * Di, hseg, L);
      // gate: y(x16) *= silu(e16 @ Wz^T)   (f16 RMW epilogue, prefetched)
      gemm16_kernel<3,0,0,1><<<dim3(8, gy), blk, 0, stream>>>(
          e16, Dm, Wz, Dm, nullptr, nullptr, 0, x16, Di, Di, TT);
      // out_proj: [TT,1024] x [512,1024] -> e += (residual accumulate, prefetched)
      gemm16_kernel<0,1,1,0><<<dim3(4, gy), blk, 0, stream>>>(
          x16, Di, opw16 + (size_t)wi * Dm * Di, Di, nullptr,
          e, Dm, nullptr, 0, Dm, TT);
    }
    // e = LN(e) (mf+mr already accumulated); regenerate e16
    add_ln_kernel<<<TT / 4, blk, 0, stream>>>(e, nullptr, norm1_w + l * Dm, norm1_b + l * Dm, e16);
    // FFN: conv1 relu -> h16 (aliases xi16)
    gemm16_kernel<1,0,0,1><<<dim3(4, gy), blk, 0, stream>>>(
        e16, Dm, c1w16 + (size_t)l * Dm * Dm, Dm, conv1_b + l * Dm,
        nullptr, 0, h16, Dm, Dm, TT);
    // conv2 -> ftmp f32 (aliases x16)
    gemm16_kernel<0,0,1,0><<<dim3(4, gy), blk, 0, stream>>>(
        h16, Dm, c2w16 + (size_t)l * Dm * Dm, Dm, conv2_b + l * Dm,
        ftmp, Dm, nullptr, 0, Dm, TT);
    add_ln_kernel<<<TT / 4, blk, 0, stream>>>(e, ftmp, norm2_w + l * Dm, norm2_b + l * Dm, e16);
  }

  add_ln_kernel<<<TT / 4, blk, 0, stream>>>(e, nullptr, normf_w, normf_b, e16);
  // proj: [TT,512] x [96,512] -> dec f32
  gemm16_kernel<0,0,1,0><<<dim3(1, gy), blk, 0, stream>>>(
      e16, Dm, prw16, Dm, proj_b, dec, FUTc, nullptr, 0, FUTc, TT);
  final_kernel<<<(Bb * FUTc * Nn + 255) / 256, blk, 0, stream>>>(
      dec, meanb, stdb, revin_w, revin_b, (float*)d_out);
}

// Round 17
// 2218.078 us; speedup vs baseline: 1.1191x; 1.1172x over previous
//
#include <hip/hip_runtime.h>

// SDMamba forward. All GEMMs on MFMA f16 (fp32 accumulate); conv/scan/LN fp32 math.
// Segmented scan (p1 local+sum(dt), combine, p2 rescan), 1 lane = 1 chain, 16 states
// in-lane; A_log=log(1..16) fast path (one exp + pow-tree). Conv: rolling window.
// GEMM: XCD-chunk swizzle; epilogue RMW (gate/ACC) software-pipelined prefetch;
// TN=64 tile variant for the O=64 x_proj.  [empirical best: round-12 structure]

typedef _Float16 f16;
typedef _Float16 f16x8 __attribute__((ext_vector_type(8)));
typedef _Float16 f16x4 __attribute__((ext_vector_type(4)));
typedef float    f32x4 __attribute__((ext_vector_type(4)));

template<bool B> struct BoolC { static constexpr bool value = B; };

constexpr int Bb  = 32;
constexpr int Lh  = 96;
constexpr int FUTc= 96;
constexpr int Nn  = 862;
constexpr int Dm  = 512;
constexpr int Ds  = 16;
constexpr int Di  = 1024;
constexpr int DRr = 32;
constexpr int TT  = Bb * Nn;     // 27584
constexpr int NCH = Bb * Di;     // 32768 scan chains
constexpr float EPSf = 1e-5f;

__device__ __forceinline__ float sigm(float x){ return 1.f / (1.f + __expf(-x)); }

__device__ __forceinline__ void gll16(f16* lds, const f16* g){
  __builtin_amdgcn_global_load_lds(
      (const __attribute__((address_space(1))) void*)g,
      (__attribute__((address_space(3)))       void*)lds, 16, 0, 0);
}

// ---------------- RevIN stats ----------------
__global__ __launch_bounds__(256) void stats_kernel(const float* __restrict__ x,
    float* __restrict__ meanb, float* __restrict__ stdb)
{
  int i = blockIdx.x * 256 + threadIdx.x;
  if (i >= TT) return;
  int b = i / Nn, n = i - b * Nn;
  const float* p = x + (size_t)b * Lh * Nn + n;
  float s = 0.f, sq = 0.f;
  #pragma unroll 4
  for (int l = 0; l < Lh; l++){ float v = p[(size_t)l * Nn]; s += v; sq += v * v; }
  float m = s * (1.f / Lh);
  float var = sq * (1.f / Lh) - m * m;
  meanb[i] = m;
  stdb[i]  = sqrtf(var + EPSf);
}

// ---------------- normalize + layout to [tok][L] fp16 ----------------
__global__ __launch_bounds__(256) void prep_kernel(const float* __restrict__ x,
    const float* __restrict__ meanb, const float* __restrict__ stdb,
    const float* __restrict__ rw, const float* __restrict__ rb,
    f16* __restrict__ xn16)
{
  int idx = blockIdx.x * 256 + threadIdx.x;
  if (idx >= Bb * Lh * Nn) return;
  int n  = idx % Nn;
  int bl = idx / Nn;
  int l  = bl % Lh;
  int b  = bl / Lh;
  int tok = b * Nn + n;
  float v = x[idx];
  xn16[(size_t)tok * Lh + l] = (f16)((v - meanb[tok]) / stdb[tok] * rw[n] + rb[n]);
}

// ---------------- f32 -> f16 convert ----------------
__global__ __launch_bounds__(256) void cvt_kernel(const float* __restrict__ in,
    f16* __restrict__ out, int n4)
{
  int i = blockIdx.x * 256 + threadIdx.x;
  if (i >= n4) return;
  float4 v = ((const float4*)in)[i];
  f16x4 h; h[0] = (f16)v.x; h[1] = (f16)v.y; h[2] = (f16)v.z; h[3] = (f16)v.w;
  *(f16x4*)(out + (size_t)i * 4) = h;
}

// ---------------- MFMA GEMM: C[m,o] = act(sum_k A[m,k]*W[o,k] + bias[o]) ----------------
// ACT: 0 none, 1 relu, 2 softplus (fast), 3 silu-gate-RMW on C16 (C16 *= silu(v)).
// ACC: C += (W32 path). W32/W16: write f32 C / f16 C16.
// OMIN: f32 write only for o>=OMIN at col (o-OMIN). OMAX16: f16 write only for o<OMAX16.
// TN: tile width (128 or 64).
template<int ACT, int ACC, int W32, int W16, int OMIN = 0, int OMAX16 = (1 << 30), int TN = 128>
__global__ __launch_bounds__(256) void gemm16_kernel(
    const f16* __restrict__ A, int lda,
    const f16* __restrict__ W, int K,
    const float* __restrict__ bias,
    float* __restrict__ C, int ldc,
    f16* __restrict__ C16, int ldc16,
    int O, int M)
{
  constexpr int JN = (TN == 64) ? 2 : 4;
  __shared__ f16 As[128 * 32];
  __shared__ f16 Bs[TN * 32];
  const int tid  = threadIdx.x;
  const int lane = tid & 63;
  const int w    = tid >> 6;
  const int wm   = w >> 1, wn = w & 1;
  // XCD-chunk swizzle (bijective, any nwg)
  int bid = blockIdx.y * gridDim.x + blockIdx.x;
  int nwg = gridDim.x * gridDim.y;
  int q = nwg >> 3, r = nwg & 7;
  int xcd = bid & 7, idx = bid >> 3;
  int swz = (xcd < r ? xcd * (q + 1) : r * (q + 1) + (xcd - r) * q) + idx;
  const int m0   = (swz / gridDim.x) * 128, o0 = (swz % gridDim.x) * TN;
  const int wmM  = wm * 64;
  const int wnN  = (TN == 64) ? wn * 32 : wn * 64;
  const int lm   = lane & 15, kg = lane >> 4;
  const int sr0  = w * 32 + (lane >> 2);
  const int sc   = (lane & 3) << 3;

  f32x4 acc[4][JN];
  #pragma unroll
  for (int i = 0; i < 4; i++)
    #pragma unroll
    for (int j = 0; j < JN; j++){ f32x4 z = {0.f,0.f,0.f,0.f}; acc[i][j] = z; }

  for (int k0 = 0; k0 < K; k0 += 32){
    __syncthreads();
    {
      int r0 = min(m0 + sr0,      M - 1);
      int r1 = min(m0 + sr0 + 16, M - 1);
      gll16(&As[w * 1024],       A + (size_t)r0 * lda + k0 + sc);
      gll16(&As[w * 1024 + 512], A + (size_t)r1 * lda + k0 + sc);
      if constexpr (TN == 128){
        int q0 = min(o0 + sr0,      O - 1);
        int q1 = min(o0 + sr0 + 16, O - 1);
        gll16(&Bs[w * 1024],       W + (size_t)q0 * K + k0 + sc);
        gll16(&Bs[w * 1024 + 512], W + (size_t)q1 * K + k0 + sc);
      } else {
        int q0 = min(o0 + w * 16 + (lane >> 2), O - 1);
        gll16(&Bs[w * 512],        W + (size_t)q0 * K + k0 + sc);
      }
    }
    __syncthreads();
    f16x8 af[4], bf[JN];
    #pragma unroll
    for (int f = 0; f < 4; f++)
      af[f] = *(const f16x8*)&As[(wmM + f * 16 + lm) * 32 + kg * 8];
    #pragma unroll
    for (int f = 0; f < JN; f++)
      bf[f] = *(const f16x8*)&Bs[(wnN + f * 16 + lm) * 32 + kg * 8];
    #pragma unroll
    for (int i = 0; i < 4; i++)
      #pragma unroll
      for (int j = 0; j < JN; j++)
        acc[i][j] = __builtin_amdgcn_mfma_f32_16x16x32_f16(af[i], bf[j], acc[i][j], 0, 0, 0);
  }

  // ---- epilogue with i-sliced RMW prefetch (ACT3: f16; ACC: f32) ----
  f16   pf16[2][4][JN];
  float pf32[2][4][JN];
  auto ldslice = [&](int i, int bank){
    if constexpr (ACT == 3){
      #pragma unroll
      for (int r2 = 0; r2 < 4; r2++){
        int m = min(m0 + wmM + i * 16 + kg * 4 + r2, M - 1);
        #pragma unroll
        for (int j = 0; j < JN; j++){
          int o = min(o0 + wnN + j * 16 + lm, O - 1);
          pf16[bank][r2][j] = C16[(size_t)m * ldc16 + o];
        }
      }
    }
    if constexpr (ACC == 1){
      #pragma unroll
      for (int r2 = 0; r2 < 4; r2++){
        int m = min(m0 + wmM + i * 16 + kg * 4 + r2, M - 1);
        #pragma unroll
        for (int j = 0; j < JN; j++){
          int o = min(o0 + wnN + j * 16 + lm, O - 1);
          if (o >= OMIN) pf32[bank][r2][j] = C[(size_t)m * ldc + (o - OMIN)];
        }
      }
    }
  };
  ldslice(0, 0);
  #pragma unroll
  for (int i = 0; i < 4; i++){
    if (i < 3) ldslice(i + 1, (i + 1) & 1);
    #pragma unroll
    for (int r2 = 0; r2 < 4; r2++){
      int m = m0 + wmM + i * 16 + kg * 4 + r2;
      if (m >= M) continue;
      #pragma unroll
      for (int j = 0; j < JN; j++){
        int o = o0 + wnN + j * 16 + lm;
        if (o >= O) continue;
        float v = acc[i][j][r2];
        if (bias) v += bias[o];
        if (ACT == 1) v = fmaxf(v, 0.f);
        if (ACT == 2) v = fmaxf(v, 0.f) + __logf(1.f + __expf(-fabsf(v)));
        if (ACT == 3){
          float gate = v * sigm(v);
          C16[(size_t)m * ldc16 + o] = (f16)((float)pf16[i & 1][r2][j] * gate);
        } else {
          if (W32 && o >= OMIN){
            if (ACC) v += pf32[i & 1][r2][j];
            C[(size_t)m * ldc + (o - OMIN)] = v;
          }
          if (W16 && o < OMAX16) C16[(size_t)m * ldc16 + o] = (f16)v;
        }
      }
    }
  }
}

// ---------------- depthwise causal conv (len 4) + SiLU ----------------
// 8 tokens x 8 channels per thread, rolling 4-row register window.
template<int DIR>
__global__ __launch_bounds__(256) void conv2_kernel(
    const f16* __restrict__ x16, const float* __restrict__ w,
    const float* __restrict__ cb, f16* __restrict__ xi16)
{
  constexpr int TG = 8;
  constexpr int NG = (Nn + TG - 1) / TG;       // 108 token-groups
  int idx = blockIdx.x * 256 + threadIdx.x;
  if (idx >= Bb * NG * 128) return;
  int d8 = (idx & 127) << 3;
  int gg = idx >> 7;
  int g  = gg % NG, b = gg / NG;
  int n0 = g * TG;
  const f16* base  = x16  + (size_t)b * Nn * 1024 + d8;
  f16*       obase = xi16 + (size_t)b * Nn * 1024 + d8;

  float bias[8];
  {
    float4 c0 = *(const float4*)(cb + d8), c1 = *(const float4*)(cb + d8 + 4);
    bias[0]=c0.x; bias[1]=c0.y; bias[2]=c0.z; bias[3]=c0.w;
    bias[4]=c1.x; bias[5]=c1.y; bias[6]=c1.z; bias[7]=c1.w;
  }
  float wr[4][8];
  #pragma unroll
  for (int i = 0; i < 8; i++){
    float4 wv = *(const float4*)(w + (size_t)(d8 + i) * 4);
    wr[0][i]=wv.x; wr[1][i]=wv.y; wr[2][i]=wv.z; wr[3][i]=wv.w;
  }

  f16x8 zv;
  #pragma unroll
  for (int i = 0; i < 8; i++) zv[i] = (f16)0.f;

  f16x8 win[4];
  #pragma unroll
  for (int j = 0; j < 3; j++){
    int r = DIR ? (n0 + j) : (n0 - 3 + j);
    bool ok = DIR ? (r < Nn) : (r >= 0);
    win[j] = ok ? *(const f16x8*)(base + (size_t)r * 1024) : zv;
  }
  #pragma unroll
  for (int s = 0; s < TG; s++){
    int n = n0 + s;
    if (n < Nn){
      int r = DIR ? (n + 3) : n;
      bool ok = DIR ? (r < Nn) : true;
      win[3] = ok ? *(const f16x8*)(base + (size_t)r * 1024) : zv;
      float acc[8];
      #pragma unroll
      for (int i = 0; i < 8; i++) acc[i] = bias[i];
      #pragma unroll
      for (int k = 0; k < 4; k++){
        const f16x8& rv = DIR ? win[3 - k] : win[k];
        #pragma unroll
        for (int i = 0; i < 8; i++) acc[i] = fmaf(wr[k][i], (float)rv[i], acc[i]);
      }
      f16x8 o;
      #pragma unroll
      for (int i = 0; i < 8; i++){ float a = acc[i]; o[i] = (f16)(a * sigm(a)); }
      *(f16x8*)(obase + (size_t)n * 1024) = o;
      win[0] = win[1]; win[1] = win[2]; win[2] = win[3];
    }
  }
}

// dA[j] = p^(j+1) for j=0..15 from one exp (tree, depth 4)
__device__ __forceinline__ void pow16(float pp, float* dA){
  float q2 = pp * pp, q3 = q2 * pp, q4 = q2 * q2, q8 = q4 * q4;
  dA[0] = pp;      dA[1] = q2;      dA[2] = q3;      dA[3] = q4;
  dA[4] = q4 * pp; dA[5] = q4 * q2; dA[6] = q4 * q3; dA[7] = q8;
  dA[8] = q8 * pp; dA[9] = q8 * q2; dA[10]= q8 * q3; dA[11]= q8 * q4;
  dA[12]= q8 * dA[4]; dA[13]= q8 * dA[5]; dA[14]= q8 * dA[6]; dA[15]= q8 * q8;
}

template<bool FAST>
__device__ __forceinline__ void mk_dA(float dt, float a0, const float* Aj, float* dA){
  if constexpr (FAST){
    pow16(__expf(dt * a0), dA);
  } else {
    _Pragma("unroll")
    for (int j = 0; j < 16; j++) dA[j] = __expf(dt * Aj[j]);
  }
}

// ---------------- scan pass 1: local h + sum(dt) per segment ----------------
template<int DIR>
__global__ __launch_bounds__(256, 2) void scan_p1_kernel(
    const float* __restrict__ bc, const f16* __restrict__ dt_,
    const f16* __restrict__ xi, const float* __restrict__ A_log,
    float* __restrict__ hseg, float* __restrict__ sdt, int L)
{
  const int seg = blockIdx.y;
  int chain = blockIdx.x * 256 + threadIdx.x;
  int d = chain & 1023;
  int b = __builtin_amdgcn_readfirstlane(chain >> 10);   // wave-uniform (256-aligned blocks)
  float Aj[16];
  #pragma unroll
  for (int q = 0; q < 4; q++){
    float4 al = *(const float4*)(A_log + (size_t)d * 16 + q * 4);
    Aj[q*4+0] = -__expf(al.x); Aj[q*4+1] = -__expf(al.y);
    Aj[q*4+2] = -__expf(al.z); Aj[q*4+3] = -__expf(al.w);
  }
  float a0 = Aj[0];
  int lf = 1;
  #pragma unroll
  for (int j = 1; j < 16; j++)
    lf &= (fabsf(Aj[j] - (j + 1) * a0) <= 2e-3f * (j + 1) * fabsf(a0));
  bool wfast = __all(lf);

  constexpr ptrdiff_t sBC = DIR ? -32 : 32;
  constexpr ptrdiff_t sX  = DIR ? -1024 : 1024;
  int p0 = seg * L;
  size_t tok0 = (size_t)b * Nn + (DIR ? (Nn - 1 - p0) : p0);
  const float* lBC = bc  + tok0 * 32;          // wave-uniform -> scalar loads
  const f16*   lDt = dt_ + tok0 * 1024 + d;
  const f16*   lXi = xi  + tok0 * 1024 + d;

  float h[16];
  #pragma unroll
  for (int j = 0; j < 16; j++) h[j] = 0.f;
  float sacc = 0.f;

  float dtA, xvA, dtB, xvB;
  float4 BA[4], BB[4];

  #define LOADP1(dt_r, xv_r, Bq)                                   \
    { dt_r = (float)*lDt; xv_r = (float)*lXi;                      \
      _Pragma("unroll")                                            \
      for (int q = 0; q < 4; q++) Bq[q] = *(const float4*)(lBC + 4*q); \
      lDt += sX; lXi += sX; lBC += sBC; }

  auto run = [&](auto FAST){
    auto stepv = [&](float dt, float xv, const float4* Bq){
      sacc += dt;
      float dtx = dt * xv;
      float B[16] = {Bq[0].x,Bq[0].y,Bq[0].z,Bq[0].w, Bq[1].x,Bq[1].y,Bq[1].z,Bq[1].w,
                     Bq[2].x,Bq[2].y,Bq[2].z,Bq[2].w, Bq[3].x,Bq[3].y,Bq[3].z,Bq[3].w};
      float dA[16];
      mk_dA<decltype(FAST)::value>(dt, a0, Aj, dA);
      #pragma unroll
      for (int j = 0; j < 16; j++)
        h[j] = fmaf(dA[j], h[j], dtx * B[j]);
    };
    LOADP1(dtA, xvA, BA);
    int t = 0;
    for (; t + 3 <= L; t += 2){
      LOADP1(dtB, xvB, BB);
      asm volatile("" ::: "memory");
      stepv(dtA, xvA, BA);
      LOADP1(dtA, xvA, BA);
      asm volatile("" ::: "memory");
      stepv(dtB, xvB, BB);
    }
    stepv(dtA, xvA, BA); t++;
    if (t < L){ LOADP1(dtB, xvB, BB); stepv(dtB, xvB, BB); }
  };
  if (wfast) run(BoolC<true>{}); else run(BoolC<false>{});
  #undef LOADP1

  float* hp = hseg + ((size_t)seg * NCH + chain) * 16;
  #pragma unroll
  for (int q = 0; q < 4; q++)
    *(float4*)(hp + 4*q) = make_float4(h[q*4], h[q*4+1], h[q*4+2], h[q*4+3]);
  sdt[(size_t)seg * NCH + chain] = sacc;
}

// ---------------- scan combine: hseg[s] := h_in(seg s+1), in place ----------------
__global__ __launch_bounds__(256) void scan_cb_kernel(
    const float* __restrict__ A_log, float* __restrict__ hseg,
    const float* __restrict__ sdt, int Sm1)
{
  int chain = blockIdx.x * 256 + threadIdx.x;
  int d = chain & 1023;
  float Aj[16];
  #pragma unroll
  for (int q = 0; q < 4; q++){
    float4 al = *(const float4*)(A_log + (size_t)d * 16 + q * 4);
    Aj[q*4+0] = -__expf(al.x); Aj[q*4+1] = -__expf(al.y);
    Aj[q*4+2] = -__expf(al.z); Aj[q*4+3] = -__expf(al.w);
  }
  float tacc[16];
  #pragma unroll
  for (int j = 0; j < 16; j++) tacc[j] = 0.f;
  for (int s = 0; s < Sm1; s++){
    float sd = sdt[(size_t)s * NCH + chain];
    float* hp = hseg + ((size_t)s * NCH + chain) * 16;
    #pragma unroll
    for (int q = 0; q < 4; q++){
      float4 hl = *(const float4*)(hp + 4*q);
      tacc[q*4+0] = fmaf(__expf(Aj[q*4+0] * sd), tacc[q*4+0], hl.x);
      tacc[q*4+1] = fmaf(__expf(Aj[q*4+1] * sd), tacc[q*4+1], hl.y);
      tacc[q*4+2] = fmaf(__expf(Aj[q*4+2] * sd), tacc[q*4+2], hl.z);
      tacc[q*4+3] = fmaf(__expf(Aj[q*4+3] * sd), tacc[q*4+3], hl.w);
      *(float4*)(hp + 4*q) = make_float4(tacc[q*4], tacc[q*4+1], tacc[q*4+2], tacc[q*4+3]);
    }
  }
}

// ---------------- scan pass 2: full rescan per segment, y over dt in place ----------------
template<int DIR>
__global__ __launch_bounds__(256, 2) void scan_p2_kernel(
    const float* __restrict__ bc, f16* dty, const f16* __restrict__ xi,
    const float* __restrict__ A_log, const float* __restrict__ Dp,
    const float* __restrict__ hseg, int L)
{
  const int seg = blockIdx.y;
  int chain = blockIdx.x * 256 + threadIdx.x;
  int d = chain & 1023;
  int b = __builtin_amdgcn_readfirstlane(chain >> 10);
  float Aj[16];
  #pragma unroll
  for (int q = 0; q < 4; q++){
    float4 al = *(const float4*)(A_log + (size_t)d * 16 + q * 4);
    Aj[q*4+0] = -__expf(al.x); Aj[q*4+1] = -__expf(al.y);
    Aj[q*4+2] = -__expf(al.z); Aj[q*4+3] = -__expf(al.w);
  }
  float a0 = Aj[0];
  int lf = 1;
  #pragma unroll
  for (int j = 1; j < 16; j++)
    lf &= (fabsf(Aj[j] - (j + 1) * a0) <= 2e-3f * (j + 1) * fabsf(a0));
  bool wfast = __all(lf);
  float Dpv = Dp[d];

  constexpr ptrdiff_t sBC = DIR ? -32 : 32;
  constexpr ptrdiff_t sX  = DIR ? -1024 : 1024;
  int p0 = seg * L;
  int len = Nn - p0; if (len > L) len = L;
  size_t tok0 = (size_t)b * Nn + (DIR ? (Nn - 1 - p0) : p0);
  const float* lBC = bc  + tok0 * 32;          // wave-uniform
  const f16*   lDt = dty + tok0 * 1024 + d;
  const f16*   lXi = xi  + tok0 * 1024 + d;
  f16*         pY  = dty + tok0 * 1024 + d;

  float h[16];
  if (seg){
    const float* hp = hseg + ((size_t)(seg - 1) * NCH + chain) * 16;
    #pragma unroll
    for (int q = 0; q < 4; q++){
      float4 hl = *(const float4*)(hp + 4*q);
      h[q*4+0] = hl.x; h[q*4+1] = hl.y; h[q*4+2] = hl.z; h[q*4+3] = hl.w;
    }
  } else {
    #pragma unroll
    for (int j = 0; j < 16; j++) h[j] = 0.f;
  }

  float dtA, xvA, dtB, xvB;
  float4 QA[8], QB[8];   // B (0..3) and C (4..7)

  #define LOADP2(dt_r, xv_r, Qq)                                   \
    { dt_r = (float)*lDt; xv_r = (float)*lXi;                      \
      _Pragma("unroll")                                            \
      for (int q = 0; q < 8; q++) Qq[q] = *(const float4*)(lBC + 4*q); \
      lDt += sX; lXi += sX; lBC += sBC; }

  auto run = [&](auto FAST){
    auto stepv = [&](float dt, float xv, const float4* Qq){
      float dtx = dt * xv;
      float B[16] = {Qq[0].x,Qq[0].y,Qq[0].z,Qq[0].w, Qq[1].x,Qq[1].y,Qq[1].z,Qq[1].w,
                     Qq[2].x,Qq[2].y,Qq[2].z,Qq[2].w, Qq[3].x,Qq[3].y,Qq[3].z,Qq[3].w};
      float C[16] = {Qq[4].x,Qq[4].y,Qq[4].z,Qq[4].w, Qq[5].x,Qq[5].y,Qq[5].z,Qq[5].w,
                     Qq[6].x,Qq[6].y,Qq[6].z,Qq[6].w, Qq[7].x,Qq[7].y,Qq[7].z,Qq[7].w};
      float dA[16];
      mk_dA<decltype(FAST)::value>(dt, a0, Aj, dA);
      float yv = xv * Dpv;
      #pragma unroll
      for (int j = 0; j < 16; j++){
        h[j] = fmaf(dA[j], h[j], dtx * B[j]);
        yv = fmaf(h[j], C[j], yv);
      }
      *pY = (f16)yv;
      pY += sX;
    };
    LOADP2(dtA, xvA, QA);
    int t = 0;
    for (; t + 3 <= len; t += 2){
      LOADP2(dtB, xvB, QB);
      asm volatile("" ::: "memory");
      stepv(dtA, xvA, QA);
      LOADP2(dtA, xvA, QA);
      asm volatile("" ::: "memory");
      stepv(dtB, xvB, QB);
    }
    stepv(dtA, xvA, QA); t++;
    if (t < len){ LOADP2(dtB, xvB, QB); stepv(dtB, xvB, QB); }
  };
  if (wfast) run(BoolC<true>{}); else run(BoolC<false>{});
  #undef LOADP2
}

// ---------------- (optional add) + LayerNorm; writes f32 e AND f16 e16 ----------------
__global__ __launch_bounds__(256) void add_ln_kernel(
    float* __restrict__ e, const float* __restrict__ add,
    const float* __restrict__ w, const float* __restrict__ bias,
    f16* __restrict__ e16)
{
  int wv = threadIdx.x >> 6, lane = threadIdx.x & 63;
  int tok = blockIdx.x * 4 + wv;
  float* p = e + (size_t)tok * Dm;
  float4 v0 = ((const float4*)p)[lane * 2];
  float4 v1 = ((const float4*)p)[lane * 2 + 1];
  float x[8] = {v0.x, v0.y, v0.z, v0.w, v1.x, v1.y, v1.z, v1.w};
  if (add){
    const float* q = add + (size_t)tok * Dm;
    float4 a0 = ((const float4*)q)[lane * 2];
    float4 a1 = ((const float4*)q)[lane * 2 + 1];
    x[0] += a0.x; x[1] += a0.y; x[2] += a0.z; x[3] += a0.w;
    x[4] += a1.x; x[5] += a1.y; x[6] += a1.z; x[7] += a1.w;
  }
  float s = 0.f;
  #pragma unroll
  for (int i = 0; i < 8; i++) s += x[i];
  #pragma unroll
  for (int off = 32; off; off >>= 1) s += __shfl_xor(s, off);
  float m = s * (1.f / Dm);
  float vv = 0.f;
  #pragma unroll
  for (int i = 0; i < 8; i++){ float dd = x[i] - m; vv += dd * dd; }
  #pragma unroll
  for (int off = 32; off; off >>= 1) vv += __shfl_xor(vv, off);
  float rs = rsqrtf(vv * (1.f / Dm) + EPSf);
  int db = lane * 8;
  float4 w0 = *(const float4*)(w + db),    w1 = *(const float4*)(w + db + 4);
  float4 b0 = *(const float4*)(bias + db), b1 = *(const float4*)(bias + db + 4);
  float wr[8] = {w0.x, w0.y, w0.z, w0.w, w1.x, w1.y, w1.z, w1.w};
  float br[8] = {b0.x, b0.y, b0.z, b0.w, b1.x, b1.y, b1.z, b1.w};
  float o[8];
  #pragma unroll
  for (int i = 0; i < 8; i++) o[i] = (x[i] - m) * rs * wr[i] + br[i];
  ((float4*)p)[lane * 2]     = make_float4(o[0], o[1], o[2], o[3]);
  ((float4*)p)[lane * 2 + 1] = make_float4(o[4], o[5], o[6], o[7]);
  f16x8 hv;
  #pragma unroll
  for (int i = 0; i < 8; i++) hv[i] = (f16)o[i];
  *(f16x8*)(e16 + (size_t)tok * Dm + db) = hv;
}

// ---------------- de-normalize + transpose to (B, FUT, N) ----------------
__global__ __launch_bounds__(256) void final_kernel(
    const float* __restrict__ dec, const float* __restrict__ meanb,
    const float* __restrict__ stdb, const float* __restrict__ rw,
    const float* __restrict__ rb, float* __restrict__ out)
{
  int idx = blockIdx.x * 256 + threadIdx.x;
  if (idx >= Bb * FUTc * Nn) return;
  int n  = idx % Nn;
  int bf = idx / Nn;
  int f  = bf % FUTc;
  int b  = bf / FUTc;
  int tok = b * Nn + n;
  float v = dec[(size_t)tok * FUTc + f];
  out[idx] = (v - rb[n]) / (rw[n] + 1e-10f) * stdb[tok] + meanb[tok];
}

extern "C" void kernel_launch(void* const* d_in, const int* in_sizes, int n_in,
                              void* d_out, int out_size, void* d_ws, size_t ws_size,
                              hipStream_t stream)
{
  const float* x_hist    = (const float*)d_in[0];
  const float* revin_w   = (const float*)d_in[1];
  const float* revin_b   = (const float*)d_in[2];
  const float* embed_w   = (const float*)d_in[3];
  const float* embed_b   = (const float*)d_in[4];
  const float* in_proj_w = (const float*)d_in[5];
  const float* conv_w    = (const float*)d_in[6];
  const float* conv_b    = (const float*)d_in[7];
  const float* x_proj_w  = (const float*)d_in[8];
  const float* dt_proj_w = (const float*)d_in[9];
  const float* dt_proj_b = (const float*)d_in[10];
  const float* A_log     = (const float*)d_in[11];
  const float* Dp        = (const float*)d_in[12];
  const float* out_proj_w= (const float*)d_in[13];
  const float* conv1_w   = (const float*)d_in[14];
  const float* conv1_b   = (const float*)d_in[15];
  const float* conv2_w   = (const float*)d_in[16];
  const float* conv2_b   = (const float*)d_in[17];
  const float* norm1_w   = (const float*)d_in[18];
  const float* norm1_b   = (const float*)d_in[19];
  const float* norm2_w   = (const float*)d_in[20];
  const float* norm2_b   = (const float*)d_in[21];
  const float* normf_w   = (const float*)d_in[22];
  const float* normf_b   = (const float*)d_in[23];
  const float* proj_w    = (const float*)d_in[24];
  const float* proj_b    = (const float*)d_in[25];

  // ---- workspace layout (~219 MB fixed) ----
  float* ws    = (float*)d_ws;
  float* meanb = ws;                                    // TT f32
  float* stdb  = meanb + TT;                            // TT f32
  float* e     = stdb + TT;                             // TT*512 f32
  f16*   e16   = (f16*)(e + (size_t)TT * Dm);           // TT*512 f16
  f16*   x16   = e16 + (size_t)TT * Dm;                 // TT*1024 f16 (conv in; dt; y)
  f16*   xi16  = x16 + (size_t)TT * Di;                 // TT*1024 f16 (conv out / scan in)
  float* bc32  = (float*)(xi16 + (size_t)TT * Di);      // TT*32 f32 (packed B,C)
  f16*   dt16in= (f16*)(bc32 + (size_t)TT * 32);        // TT*32 f16 (dt_in only)
  f16*   ipw16 = dt16in + (size_t)TT * 32;              // 4*2048*512
  f16*   opw16 = ipw16 + (size_t)4 * 2048 * Dm;         // 4*512*1024
  f16*   c1w16 = opw16 + (size_t)4 * Dm * Di;           // 2*512*512
  f16*   c2w16 = c1w16 + (size_t)2 * Dm * Dm;           // 2*512*512
  f16*   xpw16 = c2w16 + (size_t)2 * Dm * Dm;           // 4*64*1024
  f16*   dtw16 = xpw16 + (size_t)4 * 64 * Di;           // 4*1024*32
  f16*   emw16 = dtw16 + (size_t)4 * Di * DRr;          // 512*96
  f16*   prw16 = emw16 + (size_t)Dm * Lh;               // 96*512
  float* hseg  = (float*)(((uintptr_t)(prw16 + (size_t)FUTc * Dm) + 15) & ~(uintptr_t)15);

  size_t used = (uintptr_t)hseg - (uintptr_t)ws;
  size_t segbytes = ((size_t)NCH * 16 + NCH) * sizeof(float);
  int S = 1;
  if (ws_size > used) S = 1 + (int)((ws_size - used) / segbytes);
  if (S > 8) S = 8;
  if (S < 1) S = 1;
  const int L = (Nn + S - 1) / S;
  float* sdtb = hseg + (size_t)(S > 1 ? S - 1 : 0) * NCH * 16;

  // aliases into freed regions
  f16*   xn16  = x16;               // [TT][96] embed staging (pre-loop)
  f16*   h16   = xi16;              // [TT][512] FFN hidden (post-mamba)
  float* ftmp  = (float*)x16;       // [TT][512] f32 conv2 out
  float* dec   = (float*)x16;       // [TT][96] f32 final projection

  dim3 blk(256);
  auto cvt = [&](const float* in, f16* out, size_t n){
    int n4 = (int)(n / 4);
    cvt_kernel<<<(n4 + 255) / 256, blk, 0, stream>>>(in, out, n4);
  };
  cvt(in_proj_w,  ipw16, (size_t)4 * 2048 * Dm);
  cvt(out_proj_w, opw16, (size_t)4 * Dm * Di);
  cvt(conv1_w,    c1w16, (size_t)2 * Dm * Dm);
  cvt(conv2_w,    c2w16, (size_t)2 * Dm * Dm);
  cvt(x_proj_w,   xpw16, (size_t)4 * 64 * Di);
  cvt(dt_proj_w,  dtw16, (size_t)4 * Di * DRr);
  cvt(embed_w,    emw16, (size_t)Dm * Lh);
  cvt(proj_w,     prw16, (size_t)FUTc * Dm);

  stats_kernel<<<(TT + 255) / 256, blk, 0, stream>>>(x_hist, meanb, stdb);
  prep_kernel<<<(Bb * Lh * Nn + 255) / 256, blk, 0, stream>>>(x_hist, meanb, stdb, revin_w, revin_b, xn16);

  const int gy = (TT + 127) / 128;   // 216
  // embed: [TT,96] x [512,96] -> e (f32) + e16
  gemm16_kernel<0,0,1,1><<<dim3(4, gy), blk, 0, stream>>>(
      xn16, Lh, emw16, Lh, embed_b, e, Dm, e16, Dm, Dm, TT);

  constexpr int NG = (Nn + 7) / 8;   // conv token-groups
  const int convGrid = (Bb * NG * 128 + 255) / 256;

  for (int l = 0; l < 2; l++){
    for (int dir = 0; dir < 2; dir++){
      int wi = l * 2 + dir;
      const f16* Wx = ipw16 + (size_t)wi * 2048 * Dm;           // rows 0..1023 (x half)
      const f16* Wz = Wx + (size_t)Di * Dm;                     // rows 1024..2047 (z half)
      const float* Alw = A_log + (size_t)wi * Di * Ds;
      // in_proj x-half: [TT,512] x [1024,512] -> x16 f16
      gemm16_kernel<0,0,0,1><<<dim3(8, gy), blk, 0, stream>>>(
          e16, Dm, Wx, Dm, nullptr, nullptr, 0, x16, Di, Di, TT);
      // depthwise conv + silu: x16 -> xi16   (x16 dead after this)
      if (dir) conv2_kernel<1><<<convGrid, blk, 0, stream>>>(
                   x16, conv_w + (size_t)wi * Di * 4, conv_b + (size_t)wi * Di, xi16);
      else     conv2_kernel<0><<<convGrid, blk, 0, stream>>>(
                   x16, conv_w + (size_t)wi * Di * 4, conv_b + (size_t)wi * Di, xi16);
      // x_proj (TN=64): [TT,1024] x [64,1024] -> bc32 f32 (o>=32, packed) + dt16in f16 (o<32)
      gemm16_kernel<0,0,1,1,32,32,64><<<dim3(1, gy), blk, 0, stream>>>(
          xi16, Di, xpw16 + (size_t)wi * 64 * Di, Di, nullptr,
          bc32, 32, dt16in, 32, 64, TT);
      // dt_proj + softplus: [TT,32] x [1024,32] -> dt f16 into x16
      gemm16_kernel<2,0,0,1><<<dim3(8, gy), blk, 0, stream>>>(
          dt16in, 32, dtw16 + (size_t)wi * Di * DRr, DRr, dt_proj_b + (size_t)wi * Di,
          nullptr, 0, x16, Di, Di, TT);
      // segmented scan: pass1 + combine + pass2 (y overwrites dt in x16)
      if (S > 1){
        if (dir) scan_p1_kernel<1><<<dim3(NCH / 256, S - 1), blk, 0, stream>>>(
                     bc32, x16, xi16, Alw, hseg, sdtb, L);
        else     scan_p1_kernel<0><<<dim3(NCH / 256, S - 1), blk, 0, stream>>>(
                     bc32, x16, xi16, Alw, hseg, sdtb, L);
        scan_cb_kernel<<<NCH / 256, blk, 0, stream>>>(Alw, hseg, sdtb, S - 1);
      }
      if (dir) scan_p2_kernel<1><<<dim3(NCH / 256, S), blk, 0, stream>>>(
                   bc32, x16, xi16, Alw, Dp + (size_t)wi * Di, hseg, L);
      else     scan_p2_kernel<0><<<dim3(NCH / 256, S), blk, 0, stream>>>(
                   bc32, x16, xi16, Alw, Dp + (size_t)wi * Di, hseg, L);
      // gate: y(x16) *= silu(e16 @ Wz^T)   (f16 RMW epilogue, prefetched)
      gemm16_kernel<3,0,0,1><<<dim3(8, gy), blk, 0, stream>>>(
          e16, Dm, Wz, Dm, nullptr, nullptr, 0, x16, Di, Di, TT);
      // out_proj: [TT,1024] x [512,1024] -> e += (residual accumulate, prefetched)
      gemm16_kernel<0,1,1,0><<<dim3(4, gy), blk, 0, stream>>>(
          x16, Di, opw16 + (size_t)wi * Dm * Di, Di, nullptr,
          e, Dm, nullptr, 0, Dm, TT);
    }
    // e = LN(e) (mf+mr already accumulated); regenerate e16
    add_ln_kernel<<<TT / 4, blk, 0, stream>>>(e, nullptr, norm1_w + l * Dm, norm1_b + l * Dm, e16);
    // FFN: conv1 relu -> h16 (aliases xi16)
    gemm16_kernel<1,0,0,1><<<dim3(4, gy), blk, 0, stream>>>(
        e16, Dm, c1w16 + (size_t)l * Dm * Dm, Dm, conv1_b + l * Dm,
        nullptr, 0, h16, Dm, Dm, TT);
    // conv2 -> ftmp f32 (aliases x16)
    gemm16_kernel<0,0,1,0><<<dim3(4, gy), blk, 0, stream>>>(
        h16, Dm, c2w16 + (size_t)l * Dm * Dm, Dm, conv2_b + l * Dm,
        ftmp, Dm, nullptr, 0, Dm, TT);
    add_ln_kernel<<<TT / 4, blk, 0, stream>>>(e, ftmp, norm2_w + l * Dm, norm2_b + l * Dm, e16);
  }

  add_ln_kernel<<<TT / 4, blk, 0, stream>>>(e, nullptr, normf_w, normf_b, e16);
  // proj: [TT,512] x [96,512] -> dec f32
  gemm16_kernel<0,0,1,0><<<dim3(1, gy), blk, 0, stream>>>(
      e16, Dm, prw16, Dm, proj_b, dec, FUTc, nullptr, 0, FUTc, TT);
  final_kernel<<<(Bb * FUTc * Nn + 255) / 256, blk, 0, stream>>>(
      dec, meanb, stdb, revin_w, revin_b, (float*)d_out);
}

// Round 18
// 2192.884 us; speedup vs baseline: 1.1319x; 1.0115x over previous
//
#include <hip/hip_runtime.h>

// SDMamba forward. All GEMMs on MFMA f16 (fp32 accumulate); conv/scan/LN fp32 math.
// Segmented scan (p1 local+sum(dt), combine, p2 rescan), 1 lane = 1 chain, 16 states
// in-lane; A_log=log(1..16) fast path (one exp + pow-tree). Conv: rolling window.
// GEMM: round-12 structure (empirical best). hseg stored f16 -> segment count S
// roughly doubles within the same workspace slack (scan time ~ 1/S).

typedef _Float16 f16;
typedef _Float16 f16x8 __attribute__((ext_vector_type(8)));
typedef _Float16 f16x4 __attribute__((ext_vector_type(4)));
typedef float    f32x4 __attribute__((ext_vector_type(4)));

template<bool B> struct BoolC { static constexpr bool value = B; };

constexpr int Bb  = 32;
constexpr int Lh  = 96;
constexpr int FUTc= 96;
constexpr int Nn  = 862;
constexpr int Dm  = 512;
constexpr int Ds  = 16;
constexpr int Di  = 1024;
constexpr int DRr = 32;
constexpr int TT  = Bb * Nn;     // 27584
constexpr int NCH = Bb * Di;     // 32768 scan chains
constexpr float EPSf = 1e-5f;

__device__ __forceinline__ float sigm(float x){ return 1.f / (1.f + __expf(-x)); }

__device__ __forceinline__ void gll16(f16* lds, const f16* g){
  __builtin_amdgcn_global_load_lds(
      (const __attribute__((address_space(1))) void*)g,
      (__attribute__((address_space(3)))       void*)lds, 16, 0, 0);
}

// ---------------- RevIN stats ----------------
__global__ __launch_bounds__(256) void stats_kernel(const float* __restrict__ x,
    float* __restrict__ meanb, float* __restrict__ stdb)
{
  int i = blockIdx.x * 256 + threadIdx.x;
  if (i >= TT) return;
  int b = i / Nn, n = i - b * Nn;
  const float* p = x + (size_t)b * Lh * Nn + n;
  float s = 0.f, sq = 0.f;
  #pragma unroll 4
  for (int l = 0; l < Lh; l++){ float v = p[(size_t)l * Nn]; s += v; sq += v * v; }
  float m = s * (1.f / Lh);
  float var = sq * (1.f / Lh) - m * m;
  meanb[i] = m;
  stdb[i]  = sqrtf(var + EPSf);
}

// ---------------- normalize + layout to [tok][L] fp16 ----------------
__global__ __launch_bounds__(256) void prep_kernel(const float* __restrict__ x,
    const float* __restrict__ meanb, const float* __restrict__ stdb,
    const float* __restrict__ rw, const float* __restrict__ rb,
    f16* __restrict__ xn16)
{
  int idx = blockIdx.x * 256 + threadIdx.x;
  if (idx >= Bb * Lh * Nn) return;
  int n  = idx % Nn;
  int bl = idx / Nn;
  int l  = bl % Lh;
  int b  = bl / Lh;
  int tok = b * Nn + n;
  float v = x[idx];
  xn16[(size_t)tok * Lh + l] = (f16)((v - meanb[tok]) / stdb[tok] * rw[n] + rb[n]);
}

// ---------------- f32 -> f16 convert ----------------
__global__ __launch_bounds__(256) void cvt_kernel(const float* __restrict__ in,
    f16* __restrict__ out, int n4)
{
  int i = blockIdx.x * 256 + threadIdx.x;
  if (i >= n4) return;
  float4 v = ((const float4*)in)[i];
  f16x4 h; h[0] = (f16)v.x; h[1] = (f16)v.y; h[2] = (f16)v.z; h[3] = (f16)v.w;
  *(f16x4*)(out + (size_t)i * 4) = h;
}

// ---------------- MFMA GEMM: C[m,o] = act(sum_k A[m,k]*W[o,k] + bias[o]) ----------------
// ACT: 0 none, 1 relu, 2 softplus (fast), 3 silu-gate-RMW on C16 (C16 *= silu(v)).
// ACC: C += (W32 path). W32/W16: write f32 C / f16 C16.
// OMIN: f32 write only for o>=OMIN at col (o-OMIN). OMAX16: f16 write only for o<OMAX16.
// TN: tile width (128 or 64).
template<int ACT, int ACC, int W32, int W16, int OMIN = 0, int OMAX16 = (1 << 30), int TN = 128>
__global__ __launch_bounds__(256) void gemm16_kernel(
    const f16* __restrict__ A, int lda,
    const f16* __restrict__ W, int K,
    const float* __restrict__ bias,
    float* __restrict__ C, int ldc,
    f16* __restrict__ C16, int ldc16,
    int O, int M)
{
  constexpr int JN = (TN == 64) ? 2 : 4;
  __shared__ f16 As[128 * 32];
  __shared__ f16 Bs[TN * 32];
  const int tid  = threadIdx.x;
  const int lane = tid & 63;
  const int w    = tid >> 6;
  const int wm   = w >> 1, wn = w & 1;
  // XCD-chunk swizzle (bijective, any nwg)
  int bid = blockIdx.y * gridDim.x + blockIdx.x;
  int nwg = gridDim.x * gridDim.y;
  int q = nwg >> 3, r = nwg & 7;
  int xcd = bid & 7, idx = bid >> 3;
  int swz = (xcd < r ? xcd * (q + 1) : r * (q + 1) + (xcd - r) * q) + idx;
  const int m0   = (swz / gridDim.x) * 128, o0 = (swz % gridDim.x) * TN;
  const int wmM  = wm * 64;
  const int wnN  = (TN == 64) ? wn * 32 : wn * 64;
  const int lm   = lane & 15, kg = lane >> 4;
  const int sr0  = w * 32 + (lane >> 2);
  const int sc   = (lane & 3) << 3;

  f32x4 acc[4][JN];
  #pragma unroll
  for (int i = 0; i < 4; i++)
    #pragma unroll
    for (int j = 0; j < JN; j++){ f32x4 z = {0.f,0.f,0.f,0.f}; acc[i][j] = z; }

  for (int k0 = 0; k0 < K; k0 += 32){
    __syncthreads();
    {
      int r0 = min(m0 + sr0,      M - 1);
      int r1 = min(m0 + sr0 + 16, M - 1);
      gll16(&As[w * 1024],       A + (size_t)r0 * lda + k0 + sc);
      gll16(&As[w * 1024 + 512], A + (size_t)r1 * lda + k0 + sc);
      if constexpr (TN == 128){
        int q0 = min(o0 + sr0,      O - 1);
        int q1 = min(o0 + sr0 + 16, O - 1);
        gll16(&Bs[w * 1024],       W + (size_t)q0 * K + k0 + sc);
        gll16(&Bs[w * 1024 + 512], W + (size_t)q1 * K + k0 + sc);
      } else {
        int q0 = min(o0 + w * 16 + (lane >> 2), O - 1);
        gll16(&Bs[w * 512],        W + (size_t)q0 * K + k0 + sc);
      }
    }
    __syncthreads();
    f16x8 af[4], bf[JN];
    #pragma unroll
    for (int f = 0; f < 4; f++)
      af[f] = *(const f16x8*)&As[(wmM + f * 16 + lm) * 32 + kg * 8];
    #pragma unroll
    for (int f = 0; f < JN; f++)
      bf[f] = *(const f16x8*)&Bs[(wnN + f * 16 + lm) * 32 + kg * 8];
    #pragma unroll
    for (int i = 0; i < 4; i++)
      #pragma unroll
      for (int j = 0; j < JN; j++)
        acc[i][j] = __builtin_amdgcn_mfma_f32_16x16x32_f16(af[i], bf[j], acc[i][j], 0, 0, 0);
  }

  // ---- epilogue with i-sliced RMW prefetch (ACT3: f16; ACC: f32) ----
  f16   pf16[2][4][JN];
  float pf32[2][4][JN];
  auto ldslice = [&](int i, int bank){
    if constexpr (ACT == 3){
      #pragma unroll
      for (int r2 = 0; r2 < 4; r2++){
        int m = min(m0 + wmM + i * 16 + kg * 4 + r2, M - 1);
        #pragma unroll
        for (int j = 0; j < JN; j++){
          int o = min(o0 + wnN + j * 16 + lm, O - 1);
          pf16[bank][r2][j] = C16[(size_t)m * ldc16 + o];
        }
      }
    }
    if constexpr (ACC == 1){
      #pragma unroll
      for (int r2 = 0; r2 < 4; r2++){
        int m = min(m0 + wmM + i * 16 + kg * 4 + r2, M - 1);
        #pragma unroll
        for (int j = 0; j < JN; j++){
          int o = min(o0 + wnN + j * 16 + lm, O - 1);
          if (o >= OMIN) pf32[bank][r2][j] = C[(size_t)m * ldc + (o - OMIN)];
        }
      }
    }
  };
  ldslice(0, 0);
  #pragma unroll
  for (int i = 0; i < 4; i++){
    if (i < 3) ldslice(i + 1, (i + 1) & 1);
    #pragma unroll
    for (int r2 = 0; r2 < 4; r2++){
      int m = m0 + wmM + i * 16 + kg * 4 + r2;
      if (m >= M) continue;
      #pragma unroll
      for (int j = 0; j < JN; j++){
        int o = o0 + wnN + j * 16 + lm;
        if (o >= O) continue;
        float v = acc[i][j][r2];
        if (bias) v += bias[o];
        if (ACT == 1) v = fmaxf(v, 0.f);
        if (ACT == 2) v = fmaxf(v, 0.f) + __logf(1.f + __expf(-fabsf(v)));
        if (ACT == 3){
          float gate = v * sigm(v);
          C16[(size_t)m * ldc16 + o] = (f16)((float)pf16[i & 1][r2][j] * gate);
        } else {
          if (W32 && o >= OMIN){
            if (ACC) v += pf32[i & 1][r2][j];
            C[(size_t)m * ldc + (o - OMIN)] = v;
          }
          if (W16 && o < OMAX16) C16[(size_t)m * ldc16 + o] = (f16)v;
        }
      }
    }
  }
}

// ---------------- depthwise causal conv (len 4) + SiLU ----------------
// 8 tokens x 8 channels per thread, rolling 4-row register window.
template<int DIR>
__global__ __launch_bounds__(256) void conv2_kernel(
    const f16* __restrict__ x16, const float* __restrict__ w,
    const float* __restrict__ cb, f16* __restrict__ xi16)
{
  constexpr int TG = 8;
  constexpr int NG = (Nn + TG - 1) / TG;       // 108 token-groups
  int idx = blockIdx.x * 256 + threadIdx.x;
  if (idx >= Bb * NG * 128) return;
  int d8 = (idx & 127) << 3;
  int gg = idx >> 7;
  int g  = gg % NG, b = gg / NG;
  int n0 = g * TG;
  const f16* base  = x16  + (size_t)b * Nn * 1024 + d8;
  f16*       obase = xi16 + (size_t)b * Nn * 1024 + d8;

  float bias[8];
  {
    float4 c0 = *(const float4*)(cb + d8), c1 = *(const float4*)(cb + d8 + 4);
    bias[0]=c0.x; bias[1]=c0.y; bias[2]=c0.z; bias[3]=c0.w;
    bias[4]=c1.x; bias[5]=c1.y; bias[6]=c1.z; bias[7]=c1.w;
  }
  float wr[4][8];
  #pragma unroll
  for (int i = 0; i < 8; i++){
    float4 wv = *(const float4*)(w + (size_t)(d8 + i) * 4);
    wr[0][i]=wv.x; wr[1][i]=wv.y; wr[2][i]=wv.z; wr[3][i]=wv.w;
  }

  f16x8 zv;
  #pragma unroll
  for (int i = 0; i < 8; i++) zv[i] = (f16)0.f;

  f16x8 win[4];
  #pragma unroll
  for (int j = 0; j < 3; j++){
    int r = DIR ? (n0 + j) : (n0 - 3 + j);
    bool ok = DIR ? (r < Nn) : (r >= 0);
    win[j] = ok ? *(const f16x8*)(base + (size_t)r * 1024) : zv;
  }
  #pragma unroll
  for (int s = 0; s < TG; s++){
    int n = n0 + s;
    if (n < Nn){
      int r = DIR ? (n + 3) : n;
      bool ok = DIR ? (r < Nn) : true;
      win[3] = ok ? *(const f16x8*)(base + (size_t)r * 1024) : zv;
      float acc[8];
      #pragma unroll
      for (int i = 0; i < 8; i++) acc[i] = bias[i];
      #pragma unroll
      for (int k = 0; k < 4; k++){
        const f16x8& rv = DIR ? win[3 - k] : win[k];
        #pragma unroll
        for (int i = 0; i < 8; i++) acc[i] = fmaf(wr[k][i], (float)rv[i], acc[i]);
      }
      f16x8 o;
      #pragma unroll
      for (int i = 0; i < 8; i++){ float a = acc[i]; o[i] = (f16)(a * sigm(a)); }
      *(f16x8*)(obase + (size_t)n * 1024) = o;
      win[0] = win[1]; win[1] = win[2]; win[2] = win[3];
    }
  }
}

// dA[j] = p^(j+1) for j=0..15 from one exp (tree, depth 4)
__device__ __forceinline__ void pow16(float pp, float* dA){
  float q2 = pp * pp, q3 = q2 * pp, q4 = q2 * q2, q8 = q4 * q4;
  dA[0] = pp;      dA[1] = q2;      dA[2] = q3;      dA[3] = q4;
  dA[4] = q4 * pp; dA[5] = q4 * q2; dA[6] = q4 * q3; dA[7] = q8;
  dA[8] = q8 * pp; dA[9] = q8 * q2; dA[10]= q8 * q3; dA[11]= q8 * q4;
  dA[12]= q8 * dA[4]; dA[13]= q8 * dA[5]; dA[14]= q8 * dA[6]; dA[15]= q8 * q8;
}

template<bool FAST>
__device__ __forceinline__ void mk_dA(float dt, float a0, const float* Aj, float* dA){
  if constexpr (FAST){
    pow16(__expf(dt * a0), dA);
  } else {
    _Pragma("unroll")
    for (int j = 0; j < 16; j++) dA[j] = __expf(dt * Aj[j]);
  }
}

// ---------------- scan pass 1: local h + sum(dt) per segment (hseg f16) ----------------
template<int DIR>
__global__ __launch_bounds__(256, 2) void scan_p1_kernel(
    const float* __restrict__ bc, const f16* __restrict__ dt_,
    const f16* __restrict__ xi, const float* __restrict__ A_log,
    f16* __restrict__ hseg, float* __restrict__ sdt, int L)
{
  const int seg = blockIdx.y;
  int chain = blockIdx.x * 256 + threadIdx.x;
  int d = chain & 1023;
  int b = __builtin_amdgcn_readfirstlane(chain >> 10);   // wave-uniform (256-aligned blocks)
  float Aj[16];
  #pragma unroll
  for (int q = 0; q < 4; q++){
    float4 al = *(const float4*)(A_log + (size_t)d * 16 + q * 4);
    Aj[q*4+0] = -__expf(al.x); Aj[q*4+1] = -__expf(al.y);
    Aj[q*4+2] = -__expf(al.z); Aj[q*4+3] = -__expf(al.w);
  }
  float a0 = Aj[0];
  int lf = 1;
  #pragma unroll
  for (int j = 1; j < 16; j++)
    lf &= (fabsf(Aj[j] - (j + 1) * a0) <= 2e-3f * (j + 1) * fabsf(a0));
  bool wfast = __all(lf);

  constexpr ptrdiff_t sBC = DIR ? -32 : 32;
  constexpr ptrdiff_t sX  = DIR ? -1024 : 1024;
  int p0 = seg * L;
  size_t tok0 = (size_t)b * Nn + (DIR ? (Nn - 1 - p0) : p0);
  const float* lBC = bc  + tok0 * 32;          // wave-uniform -> scalar loads
  const f16*   lDt = dt_ + tok0 * 1024 + d;
  const f16*   lXi = xi  + tok0 * 1024 + d;

  float h[16];
  #pragma unroll
  for (int j = 0; j < 16; j++) h[j] = 0.f;
  float sacc = 0.f;

  float dtA, xvA, dtB, xvB;
  float4 BA[4], BB[4];

  #define LOADP1(dt_r, xv_r, Bq)                                   \
    { dt_r = (float)*lDt; xv_r = (float)*lXi;                      \
      _Pragma("unroll")                                            \
      for (int q = 0; q < 4; q++) Bq[q] = *(const float4*)(lBC + 4*q); \
      lDt += sX; lXi += sX; lBC += sBC; }

  auto run = [&](auto FAST){
    auto stepv = [&](float dt, float xv, const float4* Bq){
      sacc += dt;
      float dtx = dt * xv;
      float B[16] = {Bq[0].x,Bq[0].y,Bq[0].z,Bq[0].w, Bq[1].x,Bq[1].y,Bq[1].z,Bq[1].w,
                     Bq[2].x,Bq[2].y,Bq[2].z,Bq[2].w, Bq[3].x,Bq[3].y,Bq[3].z,Bq[3].w};
      float dA[16];
      mk_dA<decltype(FAST)::value>(dt, a0, Aj, dA);
      #pragma unroll
      for (int j = 0; j < 16; j++)
        h[j] = fmaf(dA[j], h[j], dtx * B[j]);
    };
    LOADP1(dtA, xvA, BA);
    int t = 0;
    for (; t + 3 <= L; t += 2){
      LOADP1(dtB, xvB, BB);
      asm volatile("" ::: "memory");
      stepv(dtA, xvA, BA);
      LOADP1(dtA, xvA, BA);
      asm volatile("" ::: "memory");
      stepv(dtB, xvB, BB);
    }
    stepv(dtA, xvA, BA); t++;
    if (t < L){ LOADP1(dtB, xvB, BB); stepv(dtB, xvB, BB); }
  };
  if (wfast) run(BoolC<true>{}); else run(BoolC<false>{});
  #undef LOADP1

  f16* hp = hseg + ((size_t)seg * NCH + chain) * 16;
  f16x8 h0, h1;
  #pragma unroll
  for (int j = 0; j < 8; j++){ h0[j] = (f16)h[j]; h1[j] = (f16)h[j + 8]; }
  *(f16x8*)hp       = h0;
  *(f16x8*)(hp + 8) = h1;
  sdt[(size_t)seg * NCH + chain] = sacc;
}

// ---------------- scan combine: hseg[s] := h_in(seg s+1), in place (f16) ----------------
__global__ __launch_bounds__(256) void scan_cb_kernel(
    const float* __restrict__ A_log, f16* __restrict__ hseg,
    const float* __restrict__ sdt, int Sm1)
{
  int chain = blockIdx.x * 256 + threadIdx.x;
  int d = chain & 1023;
  float Aj[16];
  #pragma unroll
  for (int q = 0; q < 4; q++){
    float4 al = *(const float4*)(A_log + (size_t)d * 16 + q * 4);
    Aj[q*4+0] = -__expf(al.x); Aj[q*4+1] = -__expf(al.y);
    Aj[q*4+2] = -__expf(al.z); Aj[q*4+3] = -__expf(al.w);
  }
  float tacc[16];
  #pragma unroll
  for (int j = 0; j < 16; j++) tacc[j] = 0.f;
  for (int s = 0; s < Sm1; s++){
    float sd = sdt[(size_t)s * NCH + chain];
    f16* hp = hseg + ((size_t)s * NCH + chain) * 16;
    f16x8 a0 = *(const f16x8*)hp, a1 = *(const f16x8*)(hp + 8);
    #pragma unroll
    for (int j = 0; j < 8; j++){
      tacc[j]     = fmaf(__expf(Aj[j]     * sd), tacc[j],     (float)a0[j]);
      tacc[j + 8] = fmaf(__expf(Aj[j + 8] * sd), tacc[j + 8], (float)a1[j]);
    }
    f16x8 o0, o1;
    #pragma unroll
    for (int j = 0; j < 8; j++){ o0[j] = (f16)tacc[j]; o1[j] = (f16)tacc[j + 8]; }
    *(f16x8*)hp       = o0;
    *(f16x8*)(hp + 8) = o1;
  }
}

// ---------------- scan pass 2: full rescan per segment, y over dt in place ----------------
template<int DIR>
__global__ __launch_bounds__(256, 2) void scan_p2_kernel(
    const float* __restrict__ bc, f16* dty, const f16* __restrict__ xi,
    const float* __restrict__ A_log, const float* __restrict__ Dp,
    const f16* __restrict__ hseg, int L)
{
  const int seg = blockIdx.y;
  int chain = blockIdx.x * 256 + threadIdx.x;
  int d = chain & 1023;
  int b = __builtin_amdgcn_readfirstlane(chain >> 10);
  float Aj[16];
  #pragma unroll
  for (int q = 0; q < 4; q++){
    float4 al = *(const float4*)(A_log + (size_t)d * 16 + q * 4);
    Aj[q*4+0] = -__expf(al.x); Aj[q*4+1] = -__expf(al.y);
    Aj[q*4+2] = -__expf(al.z); Aj[q*4+3] = -__expf(al.w);
  }
  float a0 = Aj[0];
  int lf = 1;
  #pragma unroll
  for (int j = 1; j < 16; j++)
    lf &= (fabsf(Aj[j] - (j + 1) * a0) <= 2e-3f * (j + 1) * fabsf(a0));
  bool wfast = __all(lf);
  float Dpv = Dp[d];

  constexpr ptrdiff_t sBC = DIR ? -32 : 32;
  constexpr ptrdiff_t sX  = DIR ? -1024 : 1024;
  int p0 = seg * L;
  int len = Nn - p0; if (len > L) len = L;
  size_t tok0 = (size_t)b * Nn + (DIR ? (Nn - 1 - p0) : p0);
  const float* lBC = bc  + tok0 * 32;          // wave-uniform
  const f16*   lDt = dty + tok0 * 1024 + d;
  const f16*   lXi = xi  + tok0 * 1024 + d;
  f16*         pY  = dty + tok0 * 1024 + d;

  float h[16];
  if (seg){
    const f16* hp = hseg + ((size_t)(seg - 1) * NCH + chain) * 16;
    f16x8 a0v = *(const f16x8*)hp, a1v = *(const f16x8*)(hp + 8);
    #pragma unroll
    for (int j = 0; j < 8; j++){ h[j] = (float)a0v[j]; h[j + 8] = (float)a1v[j]; }
  } else {
    #pragma unroll
    for (int j = 0; j < 16; j++) h[j] = 0.f;
  }

  float dtA, xvA, dtB, xvB;
  float4 QA[8], QB[8];   // B (0..3) and C (4..7)

  #define LOADP2(dt_r, xv_r, Qq)                                   \
    { dt_r = (float)*lDt; xv_r = (float)*lXi;                      \
      _Pragma("unroll")                                            \
      for (int q = 0; q < 8; q++) Qq[q] = *(const float4*)(lBC + 4*q); \
      lDt += sX; lXi += sX; lBC += sBC; }

  auto run = [&](auto FAST){
    auto stepv = [&](float dt, float xv, const float4* Qq){
      float dtx = dt * xv;
      float B[16] = {Qq[0].x,Qq[0].y,Qq[0].z,Qq[0].w, Qq[1].x,Qq[1].y,Qq[1].z,Qq[1].w,
                     Qq[2].x,Qq[2].y,Qq[2].z,Qq[2].w, Qq[3].x,Qq[3].y,Qq[3].z,Qq[3].w};
      float C[16] = {Qq[4].x,Qq[4].y,Qq[4].z,Qq[4].w, Qq[5].x,Qq[5].y,Qq[5].z,Qq[5].w,
                     Qq[6].x,Qq[6].y,Qq[6].z,Qq[6].w, Qq[7].x,Qq[7].y,Qq[7].z,Qq[7].w};
      float dA[16];
      mk_dA<decltype(FAST)::value>(dt, a0, Aj, dA);
      float yv = xv * Dpv;
      #pragma unroll
      for (int j = 0; j < 16; j++){
        h[j] = fmaf(dA[j], h[j], dtx * B[j]);
        yv = fmaf(h[j], C[j], yv);
      }
      *pY = (f16)yv;
      pY += sX;
    };
    LOADP2(dtA, xvA, QA);
    int t = 0;
    for (; t + 3 <= len; t += 2){
      LOADP2(dtB, xvB, QB);
      asm volatile("" ::: "memory");
      stepv(dtA, xvA, QA);
      LOADP2(dtA, xvA, QA);
      asm volatile("" ::: "memory");
      stepv(dtB, xvB, QB);
    }
    stepv(dtA, xvA, QA); t++;
    if (t < len){ LOADP2(dtB, xvB, QB); stepv(dtB, xvB, QB); }
  };
  if (wfast) run(BoolC<true>{}); else run(BoolC<false>{});
  #undef LOADP2
}

// ---------------- (optional add) + LayerNorm; writes f32 e AND f16 e16 ----------------
__global__ __launch_bounds__(256) void add_ln_kernel(
    float* __restrict__ e, const float* __restrict__ add,
    const float* __restrict__ w, const float* __restrict__ bias,
    f16* __restrict__ e16)
{
  int wv = threadIdx.x >> 6, lane = threadIdx.x & 63;
  int tok = blockIdx.x * 4 + wv;
  float* p = e + (size_t)tok * Dm;
  float4 v0 = ((const float4*)p)[lane * 2];
  float4 v1 = ((const float4*)p)[lane * 2 + 1];
  float x[8] = {v0.x, v0.y, v0.z, v0.w, v1.x, v1.y, v1.z, v1.w};
  if (add){
    const float* q = add + (size_t)tok * Dm;
    float4 a0 = ((const float4*)q)[lane * 2];
    float4 a1 = ((const float4*)q)[lane * 2 + 1];
    x[0] += a0.x; x[1] += a0.y; x[2] += a0.z; x[3] += a0.w;
    x[4] += a1.x; x[5] += a1.y; x[6] += a1.z; x[7] += a1.w;
  }
  float s = 0.f;
  #pragma unroll
  for (int i = 0; i < 8; i++) s += x[i];
  #pragma unroll
  for (int off = 32; off; off >>= 1) s += __shfl_xor(s, off);
  float m = s * (1.f / Dm);
  float vv = 0.f;
  #pragma unroll
  for (int i = 0; i < 8; i++){ float dd = x[i] - m; vv += dd * dd; }
  #pragma unroll
  for (int off = 32; off; off >>= 1) vv += __shfl_xor(vv, off);
  float rs = rsqrtf(vv * (1.f / Dm) + EPSf);
  int db = lane * 8;
  float4 w0 = *(const float4*)(w + db),    w1 = *(const float4*)(w + db + 4);
  float4 b0 = *(const float4*)(bias + db), b1 = *(const float4*)(bias + db + 4);
  float wr[8] = {w0.x, w0.y, w0.z, w0.w, w1.x, w1.y, w1.z, w1.w};
  float br[8] = {b0.x, b0.y, b0.z, b0.w, b1.x, b1.y, b1.z, b1.w};
  float o[8];
  #pragma unroll
  for (int i = 0; i < 8; i++) o[i] = (x[i] - m) * rs * wr[i] + br[i];
  ((float4*)p)[lane * 2]     = make_float4(o[0], o[1], o[2], o[3]);
  ((float4*)p)[lane * 2 + 1] = make_float4(o[4], o[5], o[6], o[7]);
  f16x8 hv;
  #pragma unroll
  for (int i = 0; i < 8; i++) hv[i] = (f16)o[i];
  *(f16x8*)(e16 + (size_t)tok * Dm + db) = hv;
}

// ---------------- de-normalize + transpose to (B, FUT, N) ----------------
__global__ __launch_bounds__(256) void final_kernel(
    const float* __restrict__ dec, const float* __restrict__ meanb,
    const float* __restrict__ stdb, const float* __restrict__ rw,
    const float* __restrict__ rb, float* __restrict__ out)
{
  int idx = blockIdx.x * 256 + threadIdx.x;
  if (idx >= Bb * FUTc * Nn) return;
  int n  = idx % Nn;
  int bf = idx / Nn;
  int f  = bf % FUTc;
  int b  = bf / FUTc;
  int tok = b * Nn + n;
  float v = dec[(size_t)tok * FUTc + f];
  out[idx] = (v - rb[n]) / (rw[n] + 1e-10f) * stdb[tok] + meanb[tok];
}

extern "C" void kernel_launch(void* const* d_in, const int* in_sizes, int n_in,
                              void* d_out, int out_size, void* d_ws, size_t ws_size,
                              hipStream_t stream)
{
  const float* x_hist    = (const float*)d_in[0];
  const float* revin_w   = (const float*)d_in[1];
  const float* revin_b   = (const float*)d_in[2];
  const float* embed_w   = (const float*)d_in[3];
  const float* embed_b   = (const float*)d_in[4];
  const float* in_proj_w = (const float*)d_in[5];
  const float* conv_w    = (const float*)d_in[6];
  const float* conv_b    = (const float*)d_in[7];
  const float* x_proj_w  = (const float*)d_in[8];
  const float* dt_proj_w = (const float*)d_in[9];
  const float* dt_proj_b = (const float*)d_in[10];
  const float* A_log     = (const float*)d_in[11];
  const float* Dp        = (const float*)d_in[12];
  const float* out_proj_w= (const float*)d_in[13];
  const float* conv1_w   = (const float*)d_in[14];
  const float* conv1_b   = (const float*)d_in[15];
  const float* conv2_w   = (const float*)d_in[16];
  const float* conv2_b   = (const float*)d_in[17];
  const float* norm1_w   = (const float*)d_in[18];
  const float* norm1_b   = (const float*)d_in[19];
  const float* norm2_w   = (const float*)d_in[20];
  const float* norm2_b   = (const float*)d_in[21];
  const float* normf_w   = (const float*)d_in[22];
  const float* normf_b   = (const float*)d_in[23];
  const float* proj_w    = (const float*)d_in[24];
  const float* proj_b    = (const float*)d_in[25];

  // ---- workspace layout (~219 MB fixed) ----
  float* ws    = (float*)d_ws;
  float* meanb = ws;                                    // TT f32
  float* stdb  = meanb + TT;                            // TT f32
  float* e     = stdb + TT;                             // TT*512 f32
  f16*   e16   = (f16*)(e + (size_t)TT * Dm);           // TT*512 f16
  f16*   x16   = e16 + (size_t)TT * Dm;                 // TT*1024 f16 (conv in; dt; y)
  f16*   xi16  = x16 + (size_t)TT * Di;                 // TT*1024 f16 (conv out / scan in)
  float* bc32  = (float*)(xi16 + (size_t)TT * Di);      // TT*32 f32 (packed B,C)
  f16*   dt16in= (f16*)(bc32 + (size_t)TT * 32);        // TT*32 f16 (dt_in only)
  f16*   ipw16 = dt16in + (size_t)TT * 32;              // 4*2048*512
  f16*   opw16 = ipw16 + (size_t)4 * 2048 * Dm;         // 4*512*1024
  f16*   c1w16 = opw16 + (size_t)4 * Dm * Di;           // 2*512*512
  f16*   c2w16 = c1w16 + (size_t)2 * Dm * Dm;           // 2*512*512
  f16*   xpw16 = c2w16 + (size_t)2 * Dm * Dm;           // 4*64*1024
  f16*   dtw16 = xpw16 + (size_t)4 * 64 * Di;           // 4*1024*32
  f16*   emw16 = dtw16 + (size_t)4 * Di * DRr;          // 512*96
  f16*   prw16 = emw16 + (size_t)Dm * Lh;               // 96*512
  f16*   hseg16= (f16*)(((uintptr_t)(prw16 + (size_t)FUTc * Dm) + 15) & ~(uintptr_t)15);

  size_t used = (uintptr_t)hseg16 - (uintptr_t)ws;
  size_t segbytes = (size_t)NCH * 16 * sizeof(f16) + (size_t)NCH * sizeof(float);
  int S = 1;
  if (ws_size > used) S = 1 + (int)((ws_size - used) / segbytes);
  if (S > 8) S = 8;
  if (S < 1) S = 1;
  const int L = (Nn + S - 1) / S;
  float* sdtb = (float*)(hseg16 + (size_t)(S > 1 ? S - 1 : 0) * NCH * 16);

  // aliases into freed regions
  f16*   xn16  = x16;               // [TT][96] embed staging (pre-loop)
  f16*   h16   = xi16;              // [TT][512] FFN hidden (post-mamba)
  float* ftmp  = (float*)x16;       // [TT][512] f32 conv2 out
  float* dec   = (float*)x16;       // [TT][96] f32 final projection

  dim3 blk(256);
  auto cvt = [&](const float* in, f16* out, size_t n){
    int n4 = (int)(n / 4);
    cvt_kernel<<<(n4 + 255) / 256, blk, 0, stream>>>(in, out, n4);
  };
  cvt(in_proj_w,  ipw16, (size_t)4 * 2048 * Dm);
  cvt(out_proj_w, opw16, (size_t)4 * Dm * Di);
  cvt(conv1_w,    c1w16, (size_t)2 * Dm * Dm);
  cvt(conv2_w,    c2w16, (size_t)2 * Dm * Dm);
  cvt(x_proj_w,   xpw16, (size_t)4 * 64 * Di);
  cvt(dt_proj_w,  dtw16, (size_t)4 * Di * DRr);
  cvt(embed_w,    emw16, (size_t)Dm * Lh);
  cvt(proj_w,     prw16, (size_t)FUTc * Dm);

  stats_kernel<<<(TT + 255) / 256, blk, 0, stream>>>(x_hist, meanb, stdb);
  prep_kernel<<<(Bb * Lh * Nn + 255) / 256, blk, 0, stream>>>(x_hist, meanb, stdb, revin_w, revin_b, xn16);

  const int gy = (TT + 127) / 128;   // 216
  // embed: [TT,96] x [512,96] -> e (f32) + e16
  gemm16_kernel<0,0,1,1><<<dim3(4, gy), blk, 0, stream>>>(
      xn16, Lh, emw16, Lh, embed_b, e, Dm, e16, Dm, Dm, TT);

  constexpr int NG = (Nn + 7) / 8;   // conv token-groups
  const int convGrid = (Bb * NG * 128 + 255) / 256;

  for (int l = 0; l < 2; l++){
    for (int dir = 0; dir < 2; dir++){
      int wi = l * 2 + dir;
      const f16* Wx = ipw16 + (size_t)wi * 2048 * Dm;           // rows 0..1023 (x half)
      const f16* Wz = Wx + (size_t)Di * Dm;                     // rows 1024..2047 (z half)
      const float* Alw = A_log + (size_t)wi * Di * Ds;
      // in_proj x-half: [TT,512] x [1024,512] -> x16 f16
      gemm16_kernel<0,0,0,1><<<dim3(8, gy), blk, 0, stream>>>(
          e16, Dm, Wx, Dm, nullptr, nullptr, 0, x16, Di, Di, TT);
      // depthwise conv + silu: x16 -> xi16   (x16 dead after this)
      if (dir) conv2_kernel<1><<<convGrid, blk, 0, stream>>>(
                   x16, conv_w + (size_t)wi * Di * 4, conv_b + (size_t)wi * Di, xi16);
      else     conv2_kernel<0><<<convGrid, blk, 0, stream>>>(
                   x16, conv_w + (size_t)wi * Di * 4, conv_b + (size_t)wi * Di, xi16);
      // x_proj (TN=64): [TT,1024] x [64,1024] -> bc32 f32 (o>=32, packed) + dt16in f16 (o<32)
      gemm16_kernel<0,0,1,1,32,32,64><<<dim3(1, gy), blk, 0, stream>>>(
          xi16, Di, xpw16 + (size_t)wi * 64 * Di, Di, nullptr,
          bc32, 32, dt16in, 32, 64, TT);
      // dt_proj + softplus: [TT,32] x [1024,32] -> dt f16 into x16
      gemm16_kernel<2,0,0,1><<<dim3(8, gy), blk, 0, stream>>>(
          dt16in, 32, dtw16 + (size_t)wi * Di * DRr, DRr, dt_proj_b + (size_t)wi * Di,
          nullptr, 0, x16, Di, Di, TT);
      // segmented scan: pass1 + combine + pass2 (y overwrites dt in x16)
      if (S > 1){
        if (dir) scan_p1_kernel<1><<<dim3(NCH / 256, S - 1), blk, 0, stream>>>(
                     bc32, x16, xi16, Alw, hseg16, sdtb, L);
        else     scan_p1_kernel<0><<<dim3(NCH / 256, S - 1), blk, 0, stream>>>(
                     bc32, x16, xi16, Alw, hseg16, sdtb, L);
        scan_cb_kernel<<<NCH / 256, blk, 0, stream>>>(Alw, hseg16, sdtb, S - 1);
      }
      if (dir) scan_p2_kernel<1><<<dim3(NCH / 256, S), blk, 0, stream>>>(
                   bc32, x16, xi16, Alw, Dp + (size_t)wi * Di, hseg16, L);
      else     scan_p2_kernel<0><<<dim3(NCH / 256, S), blk, 0, stream>>>(
                   bc32, x16, xi16, Alw, Dp + (size_t)wi * Di, hseg16, L);
      // gate: y(x16) *= silu(e16 @ Wz^T)   (f16 RMW epilogue, prefetched)
      gemm16_kernel<3,0,0,1><<<dim3(8, gy), blk, 0, stream>>>(
          e16, Dm, Wz, Dm, nullptr, nullptr, 0, x16, Di, Di, TT);
      // out_proj: [TT,1024] x [512,1024] -> e += (residual accumulate, prefetched)
      gemm16_kernel<0,1,1,0><<<dim3(4, gy), blk, 0, stream>>>(
          x16, Di, opw16 + (size_t)wi * Dm * Di, Di, nullptr,
          e, Dm, nullptr, 0, Dm, TT);
    }
    // e = LN(e) (mf+mr already accumulated); regenerate e16
    add_ln_kernel<<<TT / 4, blk, 0, stream>>>(e, nullptr, norm1_w + l * Dm, norm1_b + l * Dm, e16);
    // FFN: conv1 relu -> h16 (aliases xi16)
    gemm16_kernel<1,0,0,1><<<dim3(4, gy), blk, 0, stream>>>(
        e16, Dm, c1w16 + (size_t)l * Dm * Dm, Dm, conv1_b + l * Dm,
        nullptr, 0, h16, Dm, Dm, TT);
    // conv2 -> ftmp f32 (aliases x16)
    gemm16_kernel<0,0,1,0><<<dim3(4, gy), blk, 0, stream>>>(
        h16, Dm, c2w16 + (size_t)l * Dm * Dm, Dm, conv2_b + l * Dm,
        ftmp, Dm, nullptr, 0, Dm, TT);
    add_ln_kernel<<<TT / 4, blk, 0, stream>>>(e, ftmp, norm2_w + l * Dm, norm2_b + l * Dm, e16);
  }

  add_ln_kernel<<<TT / 4, blk, 0, stream>>>(e, nullptr, normf_w, normf_b, e16);
  // proj: [TT,512] x [96,512] -> dec f32
  gemm16_kernel<0,0,1,0><<<dim3(1, gy), blk, 0, stream>>>(
      e16, Dm, prw16, Dm, proj_b, dec, FUTc, nullptr, 0, FUTc, TT);
  final_kernel<<<(Bb * FUTc * Nn + 255) / 256, blk, 0, stream>>>(
      dec, meanb, stdb, revin_w, revin_b, (float*)d_out);
}

// Round 19
// 2181.411 us; speedup vs baseline: 1.1379x; 1.0053x over previous
//
#include <hip/hip_runtime.h>

// SDMamba forward. All GEMMs on MFMA f16 (fp32 accumulate); conv/scan/LN fp32 math.
// Segmented scan (p1 local+sum(dt), combine, p2 rescan), 1 lane = 1 chain, 16 states
// in-lane; A_log=log(1..16) fast path (one exp + pow-tree). Conv: rolling window.
// GEMM: round-12 2-barrier structure with template BK (K-step): BK=64 for K%64==0
// halves barrier/drain rounds at same register pressure (k-halves processed
// sequentially); LDS 32KB still 5 blocks/CU. hseg f16.

typedef _Float16 f16;
typedef _Float16 f16x8 __attribute__((ext_vector_type(8)));
typedef _Float16 f16x4 __attribute__((ext_vector_type(4)));
typedef float    f32x4 __attribute__((ext_vector_type(4)));

template<bool B> struct BoolC { static constexpr bool value = B; };

constexpr int Bb  = 32;
constexpr int Lh  = 96;
constexpr int FUTc= 96;
constexpr int Nn  = 862;
constexpr int Dm  = 512;
constexpr int Ds  = 16;
constexpr int Di  = 1024;
constexpr int DRr = 32;
constexpr int TT  = Bb * Nn;     // 27584
constexpr int NCH = Bb * Di;     // 32768 scan chains
constexpr float EPSf = 1e-5f;

__device__ __forceinline__ float sigm(float x){ return 1.f / (1.f + __expf(-x)); }

__device__ __forceinline__ void gll16(f16* lds, const f16* g){
  __builtin_amdgcn_global_load_lds(
      (const __attribute__((address_space(1))) void*)g,
      (__attribute__((address_space(3)))       void*)lds, 16, 0, 0);
}

// ---------------- RevIN stats ----------------
__global__ __launch_bounds__(256) void stats_kernel(const float* __restrict__ x,
    float* __restrict__ meanb, float* __restrict__ stdb)
{
  int i = blockIdx.x * 256 + threadIdx.x;
  if (i >= TT) return;
  int b = i / Nn, n = i - b * Nn;
  const float* p = x + (size_t)b * Lh * Nn + n;
  float s = 0.f, sq = 0.f;
  #pragma unroll 4
  for (int l = 0; l < Lh; l++){ float v = p[(size_t)l * Nn]; s += v; sq += v * v; }
  float m = s * (1.f / Lh);
  float var = sq * (1.f / Lh) - m * m;
  meanb[i] = m;
  stdb[i]  = sqrtf(var + EPSf);
}

// ---------------- normalize + layout to [tok][L] fp16 ----------------
__global__ __launch_bounds__(256) void prep_kernel(const float* __restrict__ x,
    const float* __restrict__ meanb, const float* __restrict__ stdb,
    const float* __restrict__ rw, const float* __restrict__ rb,
    f16* __restrict__ xn16)
{
  int idx = blockIdx.x * 256 + threadIdx.x;
  if (idx >= Bb * Lh * Nn) return;
  int n  = idx % Nn;
  int bl = idx / Nn;
  int l  = bl % Lh;
  int b  = bl / Lh;
  int tok = b * Nn + n;
  float v = x[idx];
  xn16[(size_t)tok * Lh + l] = (f16)((v - meanb[tok]) / stdb[tok] * rw[n] + rb[n]);
}

// ---------------- f32 -> f16 convert ----------------
__global__ __launch_bounds__(256) void cvt_kernel(const float* __restrict__ in,
    f16* __restrict__ out, int n4)
{
  int i = blockIdx.x * 256 + threadIdx.x;
  if (i >= n4) return;
  float4 v = ((const float4*)in)[i];
  f16x4 h; h[0] = (f16)v.x; h[1] = (f16)v.y; h[2] = (f16)v.z; h[3] = (f16)v.w;
  *(f16x4*)(out + (size_t)i * 4) = h;
}

// ---------------- MFMA GEMM: C[m,o] = act(sum_k A[m,k]*W[o,k] + bias[o]) ----------------
// ACT: 0 none, 1 relu, 2 softplus (fast), 3 silu-gate-RMW on C16 (C16 *= silu(v)).
// ACC: C += (W32 path). W32/W16: write f32 C / f16 C16.
// OMIN: f32 write only for o>=OMIN at col (o-OMIN). OMAX16: f16 write only for o<OMAX16.
// TN: tile width (128 or 64). BK: K-step per barrier round (32 or 64; K%BK==0).
template<int ACT, int ACC, int W32, int W16, int OMIN = 0, int OMAX16 = (1 << 30),
         int TN = 128, int BK = 32>
__global__ __launch_bounds__(256) void gemm16_kernel(
    const f16* __restrict__ A, int lda,
    const f16* __restrict__ W, int K,
    const float* __restrict__ bias,
    float* __restrict__ C, int ldc,
    f16* __restrict__ C16, int ldc16,
    int O, int M)
{
  constexpr int JN  = (TN == 64) ? 2 : 4;
  constexpr int LPR = BK / 8;          // lanes per row in one gll16 call (4 or 8)
  constexpr int RPC = 64 / LPR;        // rows per gll16 call (16 or 8)
  constexpr int NCA = 32 / RPC;        // A calls per wave (2 or 4)
  constexpr int NCB = (TN == 64) ? (16 / RPC > 0 ? 16 / RPC : 1) : NCA;
  __shared__ f16 As[128 * BK];
  __shared__ f16 Bs[TN * BK];
  const int tid  = threadIdx.x;
  const int lane = tid & 63;
  const int w    = tid >> 6;
  const int wm   = w >> 1, wn = w & 1;
  // XCD-chunk swizzle (bijective, any nwg)
  int bid = blockIdx.y * gridDim.x + blockIdx.x;
  int nwg = gridDim.x * gridDim.y;
  int q = nwg >> 3, r = nwg & 7;
  int xcd = bid & 7, idx = bid >> 3;
  int swz = (xcd < r ? xcd * (q + 1) : r * (q + 1) + (xcd - r) * q) + idx;
  const int m0   = (swz / gridDim.x) * 128, o0 = (swz % gridDim.x) * TN;
  const int wmM  = wm * 64;
  const int wnN  = (TN == 64) ? wn * 32 : wn * 64;
  const int lm   = lane & 15, kg = lane >> 4;
  const int lrow = lane / LPR;          // row-in-call
  const int lcol = (lane % LPR) * 8;    // col offset (halves)

  f32x4 acc[4][JN];
  #pragma unroll
  for (int i = 0; i < 4; i++)
    #pragma unroll
    for (int j = 0; j < JN; j++){ f32x4 z = {0.f,0.f,0.f,0.f}; acc[i][j] = z; }

  for (int k0 = 0; k0 < K; k0 += BK){
    __syncthreads();
    {
      #pragma unroll
      for (int c = 0; c < NCA; c++){
        int r0 = min(m0 + w * 32 + c * RPC + lrow, M - 1);
        gll16(&As[(size_t)(w * 32 + c * RPC) * BK], A + (size_t)r0 * lda + k0 + lcol);
      }
      if constexpr (TN == 128){
        #pragma unroll
        for (int c = 0; c < NCA; c++){
          int q0 = min(o0 + w * 32 + c * RPC + lrow, O - 1);
          gll16(&Bs[(size_t)(w * 32 + c * RPC) * BK], W + (size_t)q0 * K + k0 + lcol);
        }
      } else {
        #pragma unroll
        for (int c = 0; c < NCB; c++){
          int q0 = min(o0 + w * 16 + c * RPC + lrow, O - 1);
          gll16(&Bs[(size_t)(w * 16 + c * RPC) * BK], W + (size_t)q0 * K + k0 + lcol);
        }
      }
    }
    __syncthreads();
    #pragma unroll
    for (int kk = 0; kk < BK / 32; kk++){
      f16x8 af[4], bf[JN];
      #pragma unroll
      for (int f = 0; f < 4; f++)
        af[f] = *(const f16x8*)&As[(size_t)(wmM + f * 16 + lm) * BK + kk * 32 + kg * 8];
      #pragma unroll
      for (int f = 0; f < JN; f++)
        bf[f] = *(const f16x8*)&Bs[(size_t)(wnN + f * 16 + lm) * BK + kk * 32 + kg * 8];
      #pragma unroll
      for (int i = 0; i < 4; i++)
        #pragma unroll
        for (int j = 0; j < JN; j++)
          acc[i][j] = __builtin_amdgcn_mfma_f32_16x16x32_f16(af[i], bf[j], acc[i][j], 0, 0, 0);
    }
  }

  // ---- epilogue with i-sliced RMW prefetch (ACT3: f16; ACC: f32) ----
  f16   pf16[2][4][JN];
  float pf32[2][4][JN];
  auto ldslice = [&](int i, int bank){
    if constexpr (ACT == 3){
      #pragma unroll
      for (int r2 = 0; r2 < 4; r2++){
        int m = min(m0 + wmM + i * 16 + kg * 4 + r2, M - 1);
        #pragma unroll
        for (int j = 0; j < JN; j++){
          int o = min(o0 + wnN + j * 16 + lm, O - 1);
          pf16[bank][r2][j] = C16[(size_t)m * ldc16 + o];
        }
      }
    }
    if constexpr (ACC == 1){
      #pragma unroll
      for (int r2 = 0; r2 < 4; r2++){
        int m = min(m0 + wmM + i * 16 + kg * 4 + r2, M - 1);
        #pragma unroll
        for (int j = 0; j < JN; j++){
          int o = min(o0 + wnN + j * 16 + lm, O - 1);
          if (o >= OMIN) pf32[bank][r2][j] = C[(size_t)m * ldc + (o - OMIN)];
        }
      }
    }
  };
  ldslice(0, 0);
  #pragma unroll
  for (int i = 0; i < 4; i++){
    if (i < 3) ldslice(i + 1, (i + 1) & 1);
    #pragma unroll
    for (int r2 = 0; r2 < 4; r2++){
      int m = m0 + wmM + i * 16 + kg * 4 + r2;
      if (m >= M) continue;
      #pragma unroll
      for (int j = 0; j < JN; j++){
        int o = o0 + wnN + j * 16 + lm;
        if (o >= O) continue;
        float v = acc[i][j][r2];
        if (bias) v += bias[o];
        if (ACT == 1) v = fmaxf(v, 0.f);
        if (ACT == 2) v = fmaxf(v, 0.f) + __logf(1.f + __expf(-fabsf(v)));
        if (ACT == 3){
          float gate = v * sigm(v);
          C16[(size_t)m * ldc16 + o] = (f16)((float)pf16[i & 1][r2][j] * gate);
        } else {
          if (W32 && o >= OMIN){
            if (ACC) v += pf32[i & 1][r2][j];
            C[(size_t)m * ldc + (o - OMIN)] = v;
          }
          if (W16 && o < OMAX16) C16[(size_t)m * ldc16 + o] = (f16)v;
        }
      }
    }
  }
}

// ---------------- depthwise causal conv (len 4) + SiLU ----------------
// 8 tokens x 8 channels per thread, rolling 4-row register window.
template<int DIR>
__global__ __launch_bounds__(256) void conv2_kernel(
    const f16* __restrict__ x16, const float* __restrict__ w,
    const float* __restrict__ cb, f16* __restrict__ xi16)
{
  constexpr int TG = 8;
  constexpr int NG = (Nn + TG - 1) / TG;       // 108 token-groups
  int idx = blockIdx.x * 256 + threadIdx.x;
  if (idx >= Bb * NG * 128) return;
  int d8 = (idx & 127) << 3;
  int gg = idx >> 7;
  int g  = gg % NG, b = gg / NG;
  int n0 = g * TG;
  const f16* base  = x16  + (size_t)b * Nn * 1024 + d8;
  f16*       obase = xi16 + (size_t)b * Nn * 1024 + d8;

  float bias[8];
  {
    float4 c0 = *(const float4*)(cb + d8), c1 = *(const float4*)(cb + d8 + 4);
    bias[0]=c0.x; bias[1]=c0.y; bias[2]=c0.z; bias[3]=c0.w;
    bias[4]=c1.x; bias[5]=c1.y; bias[6]=c1.z; bias[7]=c1.w;
  }
  float wr[4][8];
  #pragma unroll
  for (int i = 0; i < 8; i++){
    float4 wv = *(const float4*)(w + (size_t)(d8 + i) * 4);
    wr[0][i]=wv.x; wr[1][i]=wv.y; wr[2][i]=wv.z; wr[3][i]=wv.w;
  }

  f16x8 zv;
  #pragma unroll
  for (int i = 0; i < 8; i++) zv[i] = (f16)0.f;

  f16x8 win[4];
  #pragma unroll
  for (int j = 0; j < 3; j++){
    int r = DIR ? (n0 + j) : (n0 - 3 + j);
    bool ok = DIR ? (r < Nn) : (r >= 0);
    win[j] = ok ? *(const f16x8*)(base + (size_t)r * 1024) : zv;
  }
  #pragma unroll
  for (int s = 0; s < TG; s++){
    int n = n0 + s;
    if (n < Nn){
      int r = DIR ? (n + 3) : n;
      bool ok = DIR ? (r < Nn) : true;
      win[3] = ok ? *(const f16x8*)(base + (size_t)r * 1024) : zv;
      float acc[8];
      #pragma unroll
      for (int i = 0; i < 8; i++) acc[i] = bias[i];
      #pragma unroll
      for (int k = 0; k < 4; k++){
        const f16x8& rv = DIR ? win[3 - k] : win[k];
        #pragma unroll
        for (int i = 0; i < 8; i++) acc[i] = fmaf(wr[k][i], (float)rv[i], acc[i]);
      }
      f16x8 o;
      #pragma unroll
      for (int i = 0; i < 8; i++){ float a = acc[i]; o[i] = (f16)(a * sigm(a)); }
      *(f16x8*)(obase + (size_t)n * 1024) = o;
      win[0] = win[1]; win[1] = win[2]; win[2] = win[3];
    }
  }
}

// dA[j] = p^(j+1) for j=0..15 from one exp (tree, depth 4)
__device__ __forceinline__ void pow16(float pp, float* dA){
  float q2 = pp * pp, q3 = q2 * pp, q4 = q2 * q2, q8 = q4 * q4;
  dA[0] = pp;      dA[1] = q2;      dA[2] = q3;      dA[3] = q4;
  dA[4] = q4 * pp; dA[5] = q4 * q2; dA[6] = q4 * q3; dA[7] = q8;
  dA[8] = q8 * pp; dA[9] = q8 * q2; dA[10]= q8 * q3; dA[11]= q8 * q4;
  dA[12]= q8 * dA[4]; dA[13]= q8 * dA[5]; dA[14]= q8 * dA[6]; dA[15]= q8 * q8;
}

template<bool FAST>
__device__ __forceinline__ void mk_dA(float dt, float a0, const float* Aj, float* dA){
  if constexpr (FAST){
    pow16(__expf(dt * a0), dA);
  } else {
    _Pragma("unroll")
    for (int j = 0; j < 16; j++) dA[j] = __expf(dt * Aj[j]);
  }
}

// ---------------- scan pass 1: local h + sum(dt) per segment (hseg f16) ----------------
template<int DIR>
__global__ __launch_bounds__(256, 2) void scan_p1_kernel(
    const float* __restrict__ bc, const f16* __restrict__ dt_,
    const f16* __restrict__ xi, const float* __restrict__ A_log,
    f16* __restrict__ hseg, float* __restrict__ sdt, int L)
{
  const int seg = blockIdx.y;
  int chain = blockIdx.x * 256 + threadIdx.x;
  int d = chain & 1023;
  int b = __builtin_amdgcn_readfirstlane(chain >> 10);   // wave-uniform (256-aligned blocks)
  float Aj[16];
  #pragma unroll
  for (int q = 0; q < 4; q++){
    float4 al = *(const float4*)(A_log + (size_t)d * 16 + q * 4);
    Aj[q*4+0] = -__expf(al.x); Aj[q*4+1] = -__expf(al.y);
    Aj[q*4+2] = -__expf(al.z); Aj[q*4+3] = -__expf(al.w);
  }
  float a0 = Aj[0];
  int lf = 1;
  #pragma unroll
  for (int j = 1; j < 16; j++)
    lf &= (fabsf(Aj[j] - (j + 1) * a0) <= 2e-3f * (j + 1) * fabsf(a0));
  bool wfast = __all(lf);

  constexpr ptrdiff_t sBC = DIR ? -32 : 32;
  constexpr ptrdiff_t sX  = DIR ? -1024 : 1024;
  int p0 = seg * L;
  size_t tok0 = (size_t)b * Nn + (DIR ? (Nn - 1 - p0) : p0);
  const float* lBC = bc  + tok0 * 32;          // wave-uniform -> scalar loads
  const f16*   lDt = dt_ + tok0 * 1024 + d;
  const f16*   lXi = xi  + tok0 * 1024 + d;

  float h[16];
  #pragma unroll
  for (int j = 0; j < 16; j++) h[j] = 0.f;
  float sacc = 0.f;

  float dtA, xvA, dtB, xvB;
  float4 BA[4], BB[4];

  #define LOADP1(dt_r, xv_r, Bq)                                   \
    { dt_r = (float)*lDt; xv_r = (float)*lXi;                      \
      _Pragma("unroll")                                            \
      for (int q = 0; q < 4; q++) Bq[q] = *(const float4*)(lBC + 4*q); \
      lDt += sX; lXi += sX; lBC += sBC; }

  auto run = [&](auto FAST){
    auto stepv = [&](float dt, float xv, const float4* Bq){
      sacc += dt;
      float dtx = dt * xv;
      float B[16] = {Bq[0].x,Bq[0].y,Bq[0].z,Bq[0].w, Bq[1].x,Bq[1].y,Bq[1].z,Bq[1].w,
                     Bq[2].x,Bq[2].y,Bq[2].z,Bq[2].w, Bq[3].x,Bq[3].y,Bq[3].z,Bq[3].w};
      float dA[16];
      mk_dA<decltype(FAST)::value>(dt, a0, Aj, dA);
      #pragma unroll
      for (int j = 0; j < 16; j++)
        h[j] = fmaf(dA[j], h[j], dtx * B[j]);
    };
    LOADP1(dtA, xvA, BA);
    int t = 0;
    for (; t + 3 <= L; t += 2){
      LOADP1(dtB, xvB, BB);
      asm volatile("" ::: "memory");
      stepv(dtA, xvA, BA);
      LOADP1(dtA, xvA, BA);
      asm volatile("" ::: "memory");
      stepv(dtB, xvB, BB);
    }
    stepv(dtA, xvA, BA); t++;
    if (t < L){ LOADP1(dtB, xvB, BB); stepv(dtB, xvB, BB); }
  };
  if (wfast) run(BoolC<true>{}); else run(BoolC<false>{});
  #undef LOADP1

  f16* hp = hseg + ((size_t)seg * NCH + chain) * 16;
  f16x8 h0, h1;
  #pragma unroll
  for (int j = 0; j < 8; j++){ h0[j] = (f16)h[j]; h1[j] = (f16)h[j + 8]; }
  *(f16x8*)hp       = h0;
  *(f16x8*)(hp + 8) = h1;
  sdt[(size_t)seg * NCH + chain] = sacc;
}

// ---------------- scan combine: hseg[s] := h_in(seg s+1), in place (f16) ----------------
__global__ __launch_bounds__(256) void scan_cb_kernel(
    const float* __restrict__ A_log, f16* __restrict__ hseg,
    const float* __restrict__ sdt, int Sm1)
{
  int chain = blockIdx.x * 256 + threadIdx.x;
  int d = chain & 1023;
  float Aj[16];
  #pragma unroll
  for (int q = 0; q < 4; q++){
    float4 al = *(const float4*)(A_log + (size_t)d * 16 + q * 4);
    Aj[q*4+0] = -__expf(al.x); Aj[q*4+1] = -__expf(al.y);
    Aj[q*4+2] = -__expf(al.z); Aj[q*4+3] = -__expf(al.w);
  }
  float tacc[16];
  #pragma unroll
  for (int j = 0; j < 16; j++) tacc[j] = 0.f;
  for (int s = 0; s < Sm1; s++){
    float sd = sdt[(size_t)s * NCH + chain];
    f16* hp = hseg + ((size_t)s * NCH + chain) * 16;
    f16x8 a0 = *(const f16x8*)hp, a1 = *(const f16x8*)(hp + 8);
    #pragma unroll
    for (int j = 0; j < 8; j++){
      tacc[j]     = fmaf(__expf(Aj[j]     * sd), tacc[j],     (float)a0[j]);
      tacc[j + 8] = fmaf(__expf(Aj[j + 8] * sd), tacc[j + 8], (float)a1[j]);
    }
    f16x8 o0, o1;
    #pragma unroll
    for (int j = 0; j < 8; j++){ o0[j] = (f16)tacc[j]; o1[j] = (f16)tacc[j + 8]; }
    *(f16x8*)hp       = o0;
    *(f16x8*)(hp + 8) = o1;
  }
}

// ---------------- scan pass 2: full rescan per segment, y over dt in place ----------------
template<int DIR>
__global__ __launch_bounds__(256, 2) void scan_p2_kernel(
    const float* __restrict__ bc, f16* dty, const f16* __restrict__ xi,
    const float* __restrict__ A_log, const float* __restrict__ Dp,
    const f16* __restrict__ hseg, int L)
{
  const int seg = blockIdx.y;
  int chain = blockIdx.x * 256 + threadIdx.x;
  int d = chain & 1023;
  int b = __builtin_amdgcn_readfirstlane(chain >> 10);
  float Aj[16];
  #pragma unroll
  for (int q = 0; q < 4; q++){
    float4 al = *(const float4*)(A_log + (size_t)d * 16 + q * 4);
    Aj[q*4+0] = -__expf(al.x); Aj[q*4+1] = -__expf(al.y);
    Aj[q*4+2] = -__expf(al.z); Aj[q*4+3] = -__expf(al.w);
  }
  float a0 = Aj[0];
  int lf = 1;
  #pragma unroll
  for (int j = 1; j < 16; j++)
    lf &= (fabsf(Aj[j] - (j + 1) * a0) <= 2e-3f * (j + 1) * fabsf(a0));
  bool wfast = __all(lf);
  float Dpv = Dp[d];

  constexpr ptrdiff_t sBC = DIR ? -32 : 32;
  constexpr ptrdiff_t sX  = DIR ? -1024 : 1024;
  int p0 = seg * L;
  int len = Nn - p0; if (len > L) len = L;
  size_t tok0 = (size_t)b * Nn + (DIR ? (Nn - 1 - p0) : p0);
  const float* lBC = bc  + tok0 * 32;          // wave-uniform
  const f16*   lDt = dty + tok0 * 1024 + d;
  const f16*   lXi = xi  + tok0 * 1024 + d;
  f16*         pY  = dty + tok0 * 1024 + d;

  float h[16];
  if (seg){
    const f16* hp = hseg + ((size_t)(seg - 1) * NCH + chain) * 16;
    f16x8 a0v = *(const f16x8*)hp, a1v = *(const f16x8*)(hp + 8);
    #pragma unroll
    for (int j = 0; j < 8; j++){ h[j] = (float)a0v[j]; h[j + 8] = (float)a1v[j]; }
  } else {
    #pragma unroll
    for (int j = 0; j < 16; j++) h[j] = 0.f;
  }

  float dtA, xvA, dtB, xvB;
  float4 QA[8], QB[8];   // B (0..3) and C (4..7)

  #define LOADP2(dt_r, xv_r, Qq)                                   \
    { dt_r = (float)*lDt; xv_r = (float)*lXi;                      \
      _Pragma("unroll")                                            \
      for (int q = 0; q < 8; q++) Qq[q] = *(const float4*)(lBC + 4*q); \
      lDt += sX; lXi += sX; lBC += sBC; }

  auto run = [&](auto FAST){
    auto stepv = [&](float dt, float xv, const float4* Qq){
      float dtx = dt * xv;
      float B[16] = {Qq[0].x,Qq[0].y,Qq[0].z,Qq[0].w, Qq[1].x,Qq[1].y,Qq[1].z,Qq[1].w,
                     Qq[2].x,Qq[2].y,Qq[2].z,Qq[2].w, Qq[3].x,Qq[3].y,Qq[3].z,Qq[3].w};
      float C[16] = {Qq[4].x,Qq[4].y,Qq[4].z,Qq[4].w, Qq[5].x,Qq[5].y,Qq[5].z,Qq[5].w,
                     Qq[6].x,Qq[6].y,Qq[6].z,Qq[6].w, Qq[7].x,Qq[7].y,Qq[7].z,Qq[7].w};
      float dA[16];
      mk_dA<decltype(FAST)::value>(dt, a0, Aj, dA);
      float yv = xv * Dpv;
      #pragma unroll
      for (int j = 0; j < 16; j++){
        h[j] = fmaf(dA[j], h[j], dtx * B[j]);
        yv = fmaf(h[j], C[j], yv);
      }
      *pY = (f16)yv;
      pY += sX;
    };
    LOADP2(dtA, xvA, QA);
    int t = 0;
    for (; t + 3 <= len; t += 2){
      LOADP2(dtB, xvB, QB);
      asm volatile("" ::: "memory");
      stepv(dtA, xvA, QA);
      LOADP2(dtA, xvA, QA);
      asm volatile("" ::: "memory");
      stepv(dtB, xvB, QB);
    }
    stepv(dtA, xvA, QA); t++;
    if (t < len){ LOADP2(dtB, xvB, QB); stepv(dtB, xvB, QB); }
  };
  if (wfast) run(BoolC<true>{}); else run(BoolC<false>{});
  #undef LOADP2
}

// ---------------- (optional add) + LayerNorm; writes f32 e AND f16 e16 ----------------
__global__ __launch_bounds__(256) void add_ln_kernel(
    float* __restrict__ e, const float* __restrict__ add,
    const float* __restrict__ w, const float* __restrict__ bias,
    f16* __restrict__ e16)
{
  int wv = threadIdx.x >> 6, lane = threadIdx.x & 63;
  int tok = blockIdx.x * 4 + wv;
  float* p = e + (size_t)tok * Dm;
  float4 v0 = ((const float4*)p)[lane * 2];
  float4 v1 = ((const float4*)p)[lane * 2 + 1];
  float x[8] = {v0.x, v0.y, v0.z, v0.w, v1.x, v1.y, v1.z, v1.w};
  if (add){
    const float* q = add + (size_t)tok * Dm;
    float4 a0 = ((const float4*)q)[lane * 2];
    float4 a1 = ((const float4*)q)[lane * 2 + 1];
    x[0] += a0.x; x[1] += a0.y; x[2] += a0.z; x[3] += a0.w;
    x[4] += a1.x; x[5] += a1.y; x[6] += a1.z; x[7] += a1.w;
  }
  float s = 0.f;
  #pragma unroll
  for (int i = 0; i < 8; i++) s += x[i];
  #pragma unroll
  for (int off = 32; off; off >>= 1) s += __shfl_xor(s, off);
  float m = s * (1.f / Dm);
  float vv = 0.f;
  #pragma unroll
  for (int i = 0; i < 8; i++){ float dd = x[i] - m; vv += dd * dd; }
  #pragma unroll
  for (int off = 32; off; off >>= 1) vv += __shfl_xor(vv, off);
  float rs = rsqrtf(vv * (1.f / Dm) + EPSf);
  int db = lane * 8;
  float4 w0 = *(const float4*)(w + db),    w1 = *(const float4*)(w + db + 4);
  float4 b0 = *(const float4*)(bias + db), b1 = *(const float4*)(bias + db + 4);
  float wr[8] = {w0.x, w0.y, w0.z, w0.w, w1.x, w1.y, w1.z, w1.w};
  float br[8] = {b0.x, b0.y, b0.z, b0.w, b1.x, b1.y, b1.z, b1.w};
  float o[8];
  #pragma unroll
  for (int i = 0; i < 8; i++) o[i] = (x[i] - m) * rs * wr[i] + br[i];
  ((float4*)p)[lane * 2]     = make_float4(o[0], o[1], o[2], o[3]);
  ((float4*)p)[lane * 2 + 1] = make_float4(o[4], o[5], o[6], o[7]);
  f16x8 hv;
  #pragma unroll
  for (int i = 0; i < 8; i++) hv[i] = (f16)o[i];
  *(f16x8*)(e16 + (size_t)tok * Dm + db) = hv;
}

// ---------------- de-normalize + transpose to (B, FUT, N) ----------------
__global__ __launch_bounds__(256) void final_kernel(
    const float* __restrict__ dec, const float* __restrict__ meanb,
    const float* __restrict__ stdb, const float* __restrict__ rw,
    const float* __restrict__ rb, float* __restrict__ out)
{
  int idx = blockIdx.x * 256 + threadIdx.x;
  if (idx >= Bb * FUTc * Nn) return;
  int n  = idx % Nn;
  int bf = idx / Nn;
  int f  = bf % FUTc;
  int b  = bf / FUTc;
  int tok = b * Nn + n;
  float v = dec[(size_t)tok * FUTc + f];
  out[idx] = (v - rb[n]) / (rw[n] + 1e-10f) * stdb[tok] + meanb[tok];
}

extern "C" void kernel_launch(void* const* d_in, const int* in_sizes, int n_in,
                              void* d_out, int out_size, void* d_ws, size_t ws_size,
                              hipStream_t stream)
{
  const float* x_hist    = (const float*)d_in[0];
  const float* revin_w   = (const float*)d_in[1];
  const float* revin_b   = (const float*)d_in[2];
  const float* embed_w   = (const float*)d_in[3];
  const float* embed_b   = (const float*)d_in[4];
  const float* in_proj_w = (const float*)d_in[5];
  const float* conv_w    = (const float*)d_in[6];
  const float* conv_b    = (const float*)d_in[7];
  const float* x_proj_w  = (const float*)d_in[8];
  const float* dt_proj_w = (const float*)d_in[9];
  const float* dt_proj_b = (const float*)d_in[10];
  const float* A_log     = (const float*)d_in[11];
  const float* Dp        = (const float*)d_in[12];
  const float* out_proj_w= (const float*)d_in[13];
  const float* conv1_w   = (const float*)d_in[14];
  const float* conv1_b   = (const float*)d_in[15];
  const float* conv2_w   = (const float*)d_in[16];
  const float* conv2_b   = (const float*)d_in[17];
  const float* norm1_w   = (const float*)d_in[18];
  const float* norm1_b   = (const float*)d_in[19];
  const float* norm2_w   = (const float*)d_in[20];
  const float* norm2_b   = (const float*)d_in[21];
  const float* normf_w   = (const float*)d_in[22];
  const float* normf_b   = (const float*)d_in[23];
  const float* proj_w    = (const float*)d_in[24];
  const float* proj_b    = (const float*)d_in[25];

  // ---- workspace layout (~219 MB fixed) ----
  float* ws    = (float*)d_ws;
  float* meanb = ws;                                    // TT f32
  float* stdb  = meanb + TT;                            // TT f32
  float* e     = stdb + TT;                             // TT*512 f32
  f16*   e16   = (f16*)(e + (size_t)TT * Dm);           // TT*512 f16
  f16*   x16   = e16 + (size_t)TT * Dm;                 // TT*1024 f16 (conv in; dt; y)
  f16*   xi16  = x16 + (size_t)TT * Di;                 // TT*1024 f16 (conv out / scan in)
  float* bc32  = (float*)(xi16 + (size_t)TT * Di);      // TT*32 f32 (packed B,C)
  f16*   dt16in= (f16*)(bc32 + (size_t)TT * 32);        // TT*32 f16 (dt_in only)
  f16*   ipw16 = dt16in + (size_t)TT * 32;              // 4*2048*512
  f16*   opw16 = ipw16 + (size_t)4 * 2048 * Dm;         // 4*512*1024
  f16*   c1w16 = opw16 + (size_t)4 * Dm * Di;           // 2*512*512
  f16*   c2w16 = c1w16 + (size_t)2 * Dm * Dm;           // 2*512*512
  f16*   xpw16 = c2w16 + (size_t)2 * Dm * Dm;           // 4*64*1024
  f16*   dtw16 = xpw16 + (size_t)4 * 64 * Di;           // 4*1024*32
  f16*   emw16 = dtw16 + (size_t)4 * Di * DRr;          // 512*96
  f16*   prw16 = emw16 + (size_t)Dm * Lh;               // 96*512
  f16*   hseg16= (f16*)(((uintptr_t)(prw16 + (size_t)FUTc * Dm) + 15) & ~(uintptr_t)15);

  size_t used = (uintptr_t)hseg16 - (uintptr_t)ws;
  size_t segbytes = (size_t)NCH * 16 * sizeof(f16) + (size_t)NCH * sizeof(float);
  int S = 1;
  if (ws_size > used) S = 1 + (int)((ws_size - used) / segbytes);
  if (S > 8) S = 8;
  if (S < 1) S = 1;
  const int L = (Nn + S - 1) / S;
  float* sdtb = (float*)(hseg16 + (size_t)(S > 1 ? S - 1 : 0) * NCH * 16);

  // aliases into freed regions
  f16*   xn16  = x16;               // [TT][96] embed staging (pre-loop)
  f16*   h16   = xi16;              // [TT][512] FFN hidden (post-mamba)
  float* ftmp  = (float*)x16;       // [TT][512] f32 conv2 out
  float* dec   = (float*)x16;       // [TT][96] f32 final projection

  dim3 blk(256);
  auto cvt = [&](const float* in, f16* out, size_t n){
    int n4 = (int)(n / 4);
    cvt_kernel<<<(n4 + 255) / 256, blk, 0, stream>>>(in, out, n4);
  };
  cvt(in_proj_w,  ipw16, (size_t)4 * 2048 * Dm);
  cvt(out_proj_w, opw16, (size_t)4 * Dm * Di);
  cvt(conv1_w,    c1w16, (size_t)2 * Dm * Dm);
  cvt(conv2_w,    c2w16, (size_t)2 * Dm * Dm);
  cvt(x_proj_w,   xpw16, (size_t)4 * 64 * Di);
  cvt(dt_proj_w,  dtw16, (size_t)4 * Di * DRr);
  cvt(embed_w,    emw16, (size_t)Dm * Lh);
  cvt(proj_w,     prw16, (size_t)FUTc * Dm);

  stats_kernel<<<(TT + 255) / 256, blk, 0, stream>>>(x_hist, meanb, stdb);
  prep_kernel<<<(Bb * Lh * Nn + 255) / 256, blk, 0, stream>>>(x_hist, meanb, stdb, revin_w, revin_b, xn16);

  const int gy = (TT + 127) / 128;   // 216
  // embed: [TT,96] x [512,96] -> e (f32) + e16   (K=96 -> BK=32)
  gemm16_kernel<0,0,1,1><<<dim3(4, gy), blk, 0, stream>>>(
      xn16, Lh, emw16, Lh, embed_b, e, Dm, e16, Dm, Dm, TT);

  constexpr int NG = (Nn + 7) / 8;   // conv token-groups
  const int convGrid = (Bb * NG * 128 + 255) / 256;
  constexpr int BIG = (1 << 30);

  for (int l = 0; l < 2; l++){
    for (int dir = 0; dir < 2; dir++){
      int wi = l * 2 + dir;
      const f16* Wx = ipw16 + (size_t)wi * 2048 * Dm;           // rows 0..1023 (x half)
      const f16* Wz = Wx + (size_t)Di * Dm;                     // rows 1024..2047 (z half)
      const float* Alw = A_log + (size_t)wi * Di * Ds;
      // in_proj x-half: [TT,512] x [1024,512] -> x16 f16   (BK=64)
      gemm16_kernel<0,0,0,1,0,BIG,128,64><<<dim3(8, gy), blk, 0, stream>>>(
          e16, Dm, Wx, Dm, nullptr, nullptr, 0, x16, Di, Di, TT);
      // depthwise conv + silu: x16 -> xi16   (x16 dead after this)
      if (dir) conv2_kernel<1><<<convGrid, blk, 0, stream>>>(
                   x16, conv_w + (size_t)wi * Di * 4, conv_b + (size_t)wi * Di, xi16);
      else     conv2_kernel<0><<<convGrid, blk, 0, stream>>>(
                   x16, conv_w + (size_t)wi * Di * 4, conv_b + (size_t)wi * Di, xi16);
      // x_proj (TN=64, BK=64): [TT,1024] x [64,1024] -> bc32 f32 (o>=32) + dt16in f16 (o<32)
      gemm16_kernel<0,0,1,1,32,32,64,64><<<dim3(1, gy), blk, 0, stream>>>(
          xi16, Di, xpw16 + (size_t)wi * 64 * Di, Di, nullptr,
          bc32, 32, dt16in, 32, 64, TT);
      // dt_proj + softplus: [TT,32] x [1024,32] -> dt f16 into x16   (K=32 -> BK=32)
      gemm16_kernel<2,0,0,1><<<dim3(8, gy), blk, 0, stream>>>(
          dt16in, 32, dtw16 + (size_t)wi * Di * DRr, DRr, dt_proj_b + (size_t)wi * Di,
          nullptr, 0, x16, Di, Di, TT);
      // segmented scan: pass1 + combine + pass2 (y overwrites dt in x16)
      if (S > 1){
        if (dir) scan_p1_kernel<1><<<dim3(NCH / 256, S - 1), blk, 0, stream>>>(
                     bc32, x16, xi16, Alw, hseg16, sdtb, L);
        else     scan_p1_kernel<0><<<dim3(NCH / 256, S - 1), blk, 0, stream>>>(
                     bc32, x16, xi16, Alw, hseg16, sdtb, L);
        scan_cb_kernel<<<NCH / 256, blk, 0, stream>>>(Alw, hseg16, sdtb, S - 1);
      }
      if (dir) scan_p2_kernel<1><<<dim3(NCH / 256, S), blk, 0, stream>>>(
                   bc32, x16, xi16, Alw, Dp + (size_t)wi * Di, hseg16, L);
      else     scan_p2_kernel<0><<<dim3(NCH / 256, S), blk, 0, stream>>>(
                   bc32, x16, xi16, Alw, Dp + (size_t)wi * Di, hseg16, L);
      // gate: y(x16) *= silu(e16 @ Wz^T)   (f16 RMW epilogue, BK=64)
      gemm16_kernel<3,0,0,1,0,BIG,128,64><<<dim3(8, gy), blk, 0, stream>>>(
          e16, Dm, Wz, Dm, nullptr, nullptr, 0, x16, Di, Di, TT);
      // out_proj: [TT,1024] x [512,1024] -> e += (residual accumulate, BK=64)
      gemm16_kernel<0,1,1,0,0,BIG,128,64><<<dim3(4, gy), blk, 0, stream>>>(
          x16, Di, opw16 + (size_t)wi * Dm * Di, Di, nullptr,
          e, Dm, nullptr, 0, Dm, TT);
    }
    // e = LN(e) (mf+mr already accumulated); regenerate e16
    add_ln_kernel<<<TT / 4, blk, 0, stream>>>(e, nullptr, norm1_w + l * Dm, norm1_b + l * Dm, e16);
    // FFN: conv1 relu -> h16 (aliases xi16)   (BK=64)
    gemm16_kernel<1,0,0,1,0,BIG,128,64><<<dim3(4, gy), blk, 0, stream>>>(
        e16, Dm, c1w16 + (size_t)l * Dm * Dm, Dm, conv1_b + l * Dm,
        nullptr, 0, h16, Dm, Dm, TT);
    // conv2 -> ftmp f32 (aliases x16)   (BK=64)
    gemm16_kernel<0,0,1,0,0,BIG,128,64><<<dim3(4, gy), blk, 0, stream>>>(
        h16, Dm, c2w16 + (size_t)l * Dm * Dm, Dm, conv2_b + l * Dm,
        ftmp, Dm, nullptr, 0, Dm, TT);
    add_ln_kernel<<<TT / 4, blk, 0, stream>>>(e, ftmp, norm2_w + l * Dm, norm2_b + l * Dm, e16);
  }

  add_ln_kernel<<<TT / 4, blk, 0, stream>>>(e, nullptr, normf_w, normf_b, e16);
  // proj: [TT,512] x [96,512] -> dec f32   (BK=64)
  gemm16_kernel<0,0,1,0,0,BIG,128,64><<<dim3(1, gy), blk, 0, stream>>>(
      e16, Dm, prw16, Dm, proj_b, dec, FUTc, nullptr, 0, FUTc, TT);
  final_kernel<<<(Bb * FUTc * Nn + 255) / 256, blk, 0, stream>>>(
      dec, meanb, stdb, revin_w, revin_b, (float*)d_out);
}